// Round 7
// baseline (3218.840 us; speedup 1.0000x reference)
//
#include <hip/hip_runtime.h>
#include <hip/hip_fp16.h>

static constexpr int N0 = 50000;
static constexpr int N1 = 200000;
static constexpr int N2 = 100000;
static constexpr int NNZ0 = 600000;
static constexpr int NNZ1 = 1000000;
static constexpr int NNZ2 = 600000;
static constexpr int FIN = 500;

// concatenated count layout: [L0 | L1a | L1b | L2 | B1 | B2]
static constexpr int SEG_L0 = 0;
static constexpr int SEG_L1A = 50000;
static constexpr int SEG_L1B = 250000;
static constexpr int SEG_L2 = 450000;
static constexpr int SEG_B1 = 550000;
static constexpr int SEG_B2 = 600000;
static constexpr int CNT_TOT = 800000;
static constexpr int TOT_E = NNZ0 + NNZ1 + NNZ1 + NNZ2 + 2 * N1 + 3 * N2;  // 3.9M
static constexpr int SCAN_CHUNK = 4096;
static constexpr int SCAN_BLOCKS = (CNT_TOT + SCAN_CHUNK - 1) / SCAN_CHUNK;  // 196
static constexpr int BUCK_SHIFT = 10;                                        // 1024 rows/bucket
static constexpr int NBUCK = (CNT_TOT + (1 << BUCK_SHIFT) - 1) >> BUCK_SHIFT;  // 782

typedef __attribute__((ext_vector_type(8))) short bf16x8;
typedef __attribute__((ext_vector_type(8))) _Float16 f16x8;
typedef __attribute__((ext_vector_type(4))) float f32x4;

__device__ __forceinline__ unsigned short f2bf(float f) {
  unsigned int b = __float_as_uint(f);
  b = (b + 0x7FFFu + ((b >> 16) & 1u)) >> 16;   // RNE
  return (unsigned short)b;
}

// ---------- pack X0 -> binary bitmasks: 512 bits = 16 uints per row (3.2 MB, L2-resident) ----------
__global__ __launch_bounds__(256) void pack_bits_kernel(const float* __restrict__ X0,
                                                        unsigned int* __restrict__ Xbit) {
  int row = blockIdx.x * 4 + (threadIdx.x >> 6);
  if (row >= N0) return;
  int lane = threadIdx.x & 63;
  const float* xr = X0 + (long long)row * FIN;
#pragma unroll
  for (int i = 0; i < 8; ++i) {
    int c = i * 64 + lane;
    bool pred = (c < FIN) && (xr[c] != 0.0f);
    unsigned long long m = __ballot(pred);
    if (lane == 0) {
      Xbit[row * 16 + 2 * i] = (unsigned int)m;
      Xbit[row * 16 + 2 * i + 1] = (unsigned int)(m >> 32);
    }
  }
}

// ---------- pack W -> bf16 MFMA B-fragment layout: [level][kc][nb][lane][j] ----------
__global__ void pack_w_kernel(const float* __restrict__ W, unsigned short* __restrict__ Bp) {
  int g = blockIdx.x * 256 + threadIdx.x;
  if (g >= 3 * 65536) return;
  int j = g & 7;
  int lane = (g >> 3) & 63;
  int nb = (g >> 9) & 7;
  int kc = (g >> 12) & 15;
  int level = g >> 16;
  int k = kc * 32 + (lane >> 4) * 8 + j;
  int col128 = nb * 16 + (lane & 15);
  int head = level * 2 + (col128 >> 6);
  int col = col128 & 63;
  float f = 0.0f;
  if (k < FIN) f = W[((long long)head * FIN + k) * 64 + col];
  Bp[g] = f2bf(f);
}

// ---------- pack triW -> f16 B-fragment layout: [kc(2)][nb(4)][lane][j] ----------
__global__ void pack_wt_kernel(const float* __restrict__ triW, __half* __restrict__ Wt) {
  int g = blockIdx.x * 256 + threadIdx.x;
  if (g >= 4096) return;
  int j = g & 7;
  int lane = (g >> 3) & 63;
  int nb = (g >> 9) & 3;
  int kc = g >> 11;
  int k = kc * 32 + (lane >> 4) * 8 + j;
  int col = nb * 16 + (lane & 15);
  Wt[g] = __float2half(triW[k * 64 + col]);
}

// ---------- fused bit-gather(AND) + in-register bf16 expansion + MFMA ----------
template <int NSRC>
__global__ __launch_bounds__(256) void gemm_sat_kernel(
    const unsigned int* __restrict__ Xbit, const int* __restrict__ srcidx,
    const unsigned short* __restrict__ Bp, const float* __restrict__ bvec,
    const float* __restrict__ a2w, const float* __restrict__ a2b, int head_lo,
    int M, __half* __restrict__ h_lo, __half* __restrict__ h_hi,
    float* __restrict__ e_lo, float* __restrict__ e_hi) {
  __shared__ __align__(16) unsigned int Sb[256 * 20];
  const int tid = threadIdx.x;
  const int m0 = blockIdx.x * 256;
  {
    int rg = m0 + tid;
    uint4 a[4];
#pragma unroll
    for (int c = 0; c < 4; ++c) a[c] = make_uint4(0u, 0u, 0u, 0u);
    if (rg < M) {
      if (NSRC == 1) {
        const uint4* up = (const uint4*)(Xbit + (long long)rg * 16);
#pragma unroll
        for (int c = 0; c < 4; ++c) a[c] = up[c];
      } else if (NSRC == 2) {
        const uint4* up = (const uint4*)(Xbit + (long long)srcidx[2 * rg + 0] * 16);
        const uint4* vp = (const uint4*)(Xbit + (long long)srcidx[2 * rg + 1] * 16);
#pragma unroll
        for (int c = 0; c < 4; ++c) {
          uint4 u = up[c], v = vp[c];
          a[c] = make_uint4(u.x & v.x, u.y & v.y, u.z & v.z, u.w & v.w);
        }
      } else {
        const uint4* up = (const uint4*)(Xbit + (long long)srcidx[3 * rg + 0] * 16);
        const uint4* vp = (const uint4*)(Xbit + (long long)srcidx[3 * rg + 1] * 16);
        const uint4* wp = (const uint4*)(Xbit + (long long)srcidx[3 * rg + 2] * 16);
#pragma unroll
        for (int c = 0; c < 4; ++c) {
          uint4 u = up[c], v = vp[c], w = wp[c];
          a[c] = make_uint4(u.x & v.x & w.x, u.y & v.y & w.y, u.z & v.z & w.z, u.w & v.w & w.w);
        }
      }
    }
#pragma unroll
    for (int c = 0; c < 4; ++c) *(uint4*)(Sb + tid * 20 + c * 4) = a[c];
  }
  __syncthreads();

  const int wave = tid >> 6;
  const int lane = tid & 63;
  const int quad = lane >> 4;
  const int l16 = lane & 15;
  f32x4 acc[8][4];   // [nb][sub]
#pragma unroll
  for (int i = 0; i < 8; ++i)
#pragma unroll
    for (int s = 0; s < 4; ++s) acc[i][s] = (f32x4){0.f, 0.f, 0.f, 0.f};
  const bf16x8* Bf = (const bf16x8*)Bp;
#pragma unroll 2
  for (int kc = 0; kc < 16; ++kc) {
    bf16x8 af[4];
#pragma unroll
    for (int sub = 0; sub < 4; ++sub) {
      unsigned int bw = Sb[(wave * 64 + sub * 16 + l16) * 20 + kc];
      unsigned int byte = (bw >> (quad * 8)) & 0xFFu;
#pragma unroll
      for (int j = 0; j < 4; ++j) {
        unsigned int b2 = (byte >> (2 * j)) & 3u;
        ((unsigned int*)&af[sub])[j] = ((b2 & 1u) | ((b2 & 2u) << 15)) * 0x3F80u;
      }
    }
#pragma unroll
    for (int nb = 0; nb < 8; ++nb) {
      bf16x8 bf = Bf[(kc * 8 + nb) * 64 + lane];
#pragma unroll
      for (int sub = 0; sub < 4; ++sub)
        acc[nb][sub] = __builtin_amdgcn_mfma_f32_16x16x32_bf16(af[sub], bf, acc[nb][sub], 0, 0, 0);
    }
  }

  float bia[8], aw[8];
#pragma unroll
  for (int nb = 0; nb < 8; ++nb) {
    int col128 = nb * 16 + l16;
    int hh = col128 >> 6, col = col128 & 63;
    bia[nb] = bvec[(head_lo + hh) * 64 + col];
    aw[nb] = a2w[(head_lo + hh) * 64 + col];
  }
  float blo = a2b[head_lo], bhi = a2b[head_lo + 1];
#pragma unroll
  for (int sub = 0; sub < 4; ++sub) {
    float plo[4] = {0.f, 0.f, 0.f, 0.f};
    float phi[4] = {0.f, 0.f, 0.f, 0.f};
#pragma unroll
    for (int nb = 0; nb < 8; ++nb) {
      int col128 = nb * 16 + l16;
      int hh = col128 >> 6, col = col128 & 63;
      __half* hdst = hh ? h_hi : h_lo;
#pragma unroll
      for (int reg = 0; reg < 4; ++reg) {
        int rg = m0 + wave * 64 + sub * 16 + quad * 4 + reg;   // C/D: row=quad*4+reg, col=l16
        float v = acc[nb][sub][reg] + bia[nb];
        if (rg < M) hdst[(long long)rg * 64 + col] = __float2half(v);
        if (hh) phi[reg] += v * aw[nb]; else plo[reg] += v * aw[nb];
      }
    }
#pragma unroll
    for (int off = 1; off < 16; off <<= 1) {
#pragma unroll
      for (int reg = 0; reg < 4; ++reg) {
        plo[reg] += __shfl_xor(plo[reg], off);
        phi[reg] += __shfl_xor(phi[reg], off);
      }
    }
    if (l16 == 0) {
#pragma unroll
      for (int reg = 0; reg < 4; ++reg) {
        int rg = m0 + wave * 64 + sub * 16 + quad * 4 + reg;
        if (rg < M) {
          e_lo[rg] = __expf(plo[reg] + blo);   // |s2| small by construction: no max needed
          e_hi[rg] = __expf(phi[reg] + bhi);
        }
      }
    }
  }
}

// ---------- merged CSR build ----------
__global__ __launch_bounds__(256) void count_all_kernel(
    const int* __restrict__ r0, const int* __restrict__ r1a, const int* __restrict__ r1b,
    const int* __restrict__ r2, const int* __restrict__ rb1, const int* __restrict__ rb2,
    int* __restrict__ cnt) {
  int g = blockIdx.x * 256 + threadIdx.x;
  if (g >= TOT_E) return;
  int seg, r;
  if (g < 600000) { seg = SEG_L0; r = r0[g]; }
  else if (g < 1600000) { seg = SEG_L1A; r = r1a[g - 600000]; }
  else if (g < 2600000) { seg = SEG_L1B; r = r1b[g - 1600000]; }
  else if (g < 3200000) { seg = SEG_L2; r = r2[g - 2600000]; }
  else if (g < 3600000) { seg = SEG_B1; r = rb1[g - 3200000]; }
  else { seg = SEG_B2; r = rb2[g - 3600000]; }
  atomicAdd(&cnt[seg + r], 1);
}

__global__ __launch_bounds__(256) void scan_partial_kernel(const int* __restrict__ cnt,
                                                           int* __restrict__ bsum) {
  __shared__ int s[256];
  int b = blockIdx.x, t = threadIdx.x;
  int base = b * SCAN_CHUNK + t * 16;
  int sum = 0;
#pragma unroll
  for (int i = 0; i < 16; ++i) {
    int idx = base + i;
    if (idx < CNT_TOT) sum += cnt[idx];
  }
  s[t] = sum;
  __syncthreads();
  for (int off = 128; off > 0; off >>= 1) {
    if (t < off) s[t] += s[t + off];
    __syncthreads();
  }
  if (t == 0) bsum[b] = s[0];
}

__global__ __launch_bounds__(256) void scan_bsum_kernel(int* __restrict__ bsum, int nb) {
  __shared__ int s[256];
  int t = threadIdx.x;
  int v = (t < nb) ? bsum[t] : 0;
  s[t] = v;
  __syncthreads();
  for (int off = 1; off < 256; off <<= 1) {
    int u = (t >= off) ? s[t - off] : 0;
    __syncthreads();
    s[t] += u;
    __syncthreads();
  }
  if (t < nb) bsum[t] = (t == 0) ? 0 : s[t - 1];
  if (t == 0) bsum[nb] = s[nb - 1];
}

__global__ __launch_bounds__(256) void scan_write_kernel(const int* __restrict__ cnt,
                                                         const int* __restrict__ bsum,
                                                         int* __restrict__ gscan) {
  __shared__ int s[256];
  int b = blockIdx.x, t = threadIdx.x;
  int base = b * SCAN_CHUNK + t * 16;
  int loc[16];
  int sum = 0;
#pragma unroll
  for (int i = 0; i < 16; ++i) {
    int idx = base + i;
    int v = (idx < CNT_TOT) ? cnt[idx] : 0;
    loc[i] = sum;
    sum += v;
  }
  s[t] = sum;
  __syncthreads();
  for (int off = 1; off < 256; off <<= 1) {
    int u = (t >= off) ? s[t - off] : 0;
    __syncthreads();
    s[t] += u;
    __syncthreads();
  }
  int toff = bsum[b] + ((t == 0) ? 0 : s[t - 1]);
#pragma unroll
  for (int i = 0; i < 16; ++i) {
    int idx = base + i;
    if (idx < CNT_TOT) gscan[idx] = toff + loc[i];
  }
  if (b == 0 && t == 0) gscan[CNT_TOT] = bsum[SCAN_BLOCKS];
}

// ---------- pass A: append (row,val) into bucket-contiguous staging (dense writes) ----------
__global__ __launch_bounds__(256) void stage_all_kernel(
    const int* __restrict__ r0, const int* __restrict__ r1a, const int* __restrict__ r1b,
    const int* __restrict__ r2, const int* __restrict__ rb1, const int* __restrict__ rb2,
    const int* __restrict__ gscan, int* __restrict__ bcur, int2* __restrict__ stage) {
  int g = blockIdx.x * 256 + threadIdx.x;
  if (g >= TOT_E) return;
  int seg, r, val;
  if (g < 600000) { int l = g; seg = SEG_L0; r = r0[l]; val = r0[NNZ0 + l]; }
  else if (g < 1600000) { int l = g - 600000; seg = SEG_L1A; r = r1a[l]; val = r1a[NNZ1 + l]; }
  else if (g < 2600000) { int l = g - 1600000; seg = SEG_L1B; r = r1b[l]; val = r1b[NNZ1 + l]; }
  else if (g < 3200000) { int l = g - 2600000; seg = SEG_L2; r = r2[l]; val = r2[NNZ2 + l]; }
  else if (g < 3600000) { int l = g - 3200000; seg = SEG_B1; r = rb1[l]; val = l; }
  else { int l = g - 3600000; seg = SEG_B2; r = rb2[l]; val = l; }
  int row = seg + r;
  int b = row >> BUCK_SHIFT;
  int pos = gscan[b << BUCK_SHIFT] + atomicAdd(&bcur[b], 1);
  stage[pos] = make_int2(row, val);
}

// ---------- pass B: one block per bucket; LDS row-cursors; scatter within L2-resident slice ----------
__global__ __launch_bounds__(256) void fill_bucket_kernel(
    const int* __restrict__ gscan, const int2* __restrict__ stage, int* __restrict__ pool) {
  __shared__ int lcur[1 << BUCK_SHIFT];
  int b = blockIdx.x;
  int base_row = b << BUCK_SHIFT;
  int end_row = base_row + (1 << BUCK_SHIFT);
  if (end_row > CNT_TOT) end_row = CNT_TOT;
  for (int i = threadIdx.x; i < (1 << BUCK_SHIFT); i += 256) lcur[i] = 0;
  __syncthreads();
  int start = gscan[base_row], end = gscan[end_row];
  for (int i = start + threadIdx.x; i < end; i += 256) {
    int2 rv = stage[i];
    int pos = gscan[rv.x] + atomicAdd(&lcur[rv.x - base_row], 1);
    pool[pos] = rv.y;
  }
}

// ---------- dual-table gather over one CSR row, 4x unrolled for MLP ----------
__device__ __forceinline__ void dual_gather_row(
    const int* __restrict__ col, int p0, int p1, int lane,
    const float* __restrict__ ea, const __half* __restrict__ ha,
    const float* __restrict__ eb, const __half* __restrict__ hb,
    float& za, float& aa, float& zb, float& ab) {
  int p = p0;
  for (; p + 4 <= p1; p += 4) {
    int c0 = col[p + 0], c1 = col[p + 1], c2 = col[p + 2], c3 = col[p + 3];
    float wa0 = ea[c0], wa1 = ea[c1], wa2 = ea[c2], wa3 = ea[c3];
    float wb0 = eb[c0], wb1 = eb[c1], wb2 = eb[c2], wb3 = eb[c3];
    float va0 = __half2float(ha[(long long)c0 * 64 + lane]);
    float va1 = __half2float(ha[(long long)c1 * 64 + lane]);
    float va2 = __half2float(ha[(long long)c2 * 64 + lane]);
    float va3 = __half2float(ha[(long long)c3 * 64 + lane]);
    float vb0 = __half2float(hb[(long long)c0 * 64 + lane]);
    float vb1 = __half2float(hb[(long long)c1 * 64 + lane]);
    float vb2 = __half2float(hb[(long long)c2 * 64 + lane]);
    float vb3 = __half2float(hb[(long long)c3 * 64 + lane]);
    za += (wa0 + wa1) + (wa2 + wa3);
    zb += (wb0 + wb1) + (wb2 + wb3);
    aa += wa0 * va0 + wa1 * va1 + wa2 * va2 + wa3 * va3;
    ab += wb0 * vb0 + wb1 * vb1 + wb2 * vb2 + wb3 * vb3;
  }
  for (; p < p1; ++p) {
    int c = col[p];
    float wa = ea[c], wb = eb[c];
    za += wa; zb += wb;
    aa += wa * __half2float(ha[(long long)c * 64 + lane]);
    ab += wb * __half2float(hb[(long long)c * 64 + lane]);
  }
}

// ---------- SAT dual (L0, L2): one traversal, expv precomputed per node ----------
template <typename OutT>
__global__ __launch_bounds__(256) void sat_dual_z_kernel(
    const int* __restrict__ rowptr, const int* __restrict__ col,
    const float* __restrict__ ea, const __half* __restrict__ ha,
    const float* __restrict__ eb, const __half* __restrict__ hb,
    const float* __restrict__ pw, OutT* __restrict__ out, int n) {
  int row = blockIdx.x * 4 + (threadIdx.x >> 6);
  if (row >= n) return;
  int lane = threadIdx.x & 63;
  int p0 = rowptr[row], p1 = rowptr[row + 1];
  float za = 0.f, zb = 0.f, aa = 0.f, ab = 0.f;
  dual_gather_row(col, p0, p1, lane, ea, ha, eb, hb, za, aa, zb, ab);
  float r = (za > 0.f ? aa / za : 0.f) + (zb > 0.f ? ab / zb : 0.f);
  float pv = pw[0];
  r = r >= 0.f ? r : pv * r;   // prelu
  out[(long long)row * 64 + lane] = (OutT)r;
}

// ---------- H2t = H2 @ triW via f16 MFMA ----------
__global__ __launch_bounds__(256) void tri_mfma_kernel(
    const __half* __restrict__ H2, const __half* __restrict__ Wt,
    __half* __restrict__ H2t, int n) {
  const int tid = threadIdx.x;
  const int m0 = blockIdx.x * 64;
  const int wave = tid >> 6;
  const int lane = tid & 63;
  const int quad = lane >> 4;
  const int l16 = lane & 15;
  const int arow = m0 + wave * 16 + l16;
  f32x4 acc[4];
#pragma unroll
  for (int i = 0; i < 4; ++i) acc[i] = (f32x4){0.f, 0.f, 0.f, 0.f};
  const f16x8* Wf = (const f16x8*)Wt;
#pragma unroll
  for (int kc = 0; kc < 2; ++kc) {
    f16x8 af = (f16x8){0, 0, 0, 0, 0, 0, 0, 0};
    if (arow < n) af = *(const f16x8*)((const _Float16*)H2 + (long long)arow * 64 + kc * 32 + quad * 8);
#pragma unroll
    for (int nb = 0; nb < 4; ++nb) {
      f16x8 bf = Wf[(kc * 4 + nb) * 64 + lane];
      acc[nb] = __builtin_amdgcn_mfma_f32_16x16x32_f16(af, bf, acc[nb], 0, 0, 0);
    }
  }
#pragma unroll
  for (int nb = 0; nb < 4; ++nb) {
    int col = nb * 16 + l16;
#pragma unroll
    for (int reg = 0; reg < 4; ++reg) {
      int rg = m0 + wave * 16 + quad * 4 + reg;
      if (rg < n) H2t[(long long)rg * 64 + col] = __float2half(acc[nb][reg]);
    }
  }
}

// ---------- mega edge-row kernel: G = prelu(satL1a + satL1b) + trib + B2 @ H2t ----------
__global__ __launch_bounds__(256) void sat_l1_mega_kernel(
    const int* __restrict__ rp_a, const int* __restrict__ rp_b, const int* __restrict__ rp_B2,
    const int* __restrict__ pool,
    const float* __restrict__ ea, const __half* __restrict__ ha,
    const float* __restrict__ eb, const __half* __restrict__ hb,
    const __half* __restrict__ H2t, const float* __restrict__ trib,
    const float* __restrict__ pw, __half* __restrict__ G, int n) {
  int row = blockIdx.x * 4 + (threadIdx.x >> 6);
  if (row >= n) return;
  int lane = threadIdx.x & 63;
  // head a, 4x unrolled
  float za = 0.f, aa = 0.f;
  {
    int p0 = rp_a[row], p1 = rp_a[row + 1];
    int p = p0;
    for (; p + 4 <= p1; p += 4) {
      int c0 = pool[p + 0], c1 = pool[p + 1], c2 = pool[p + 2], c3 = pool[p + 3];
      float w0 = ea[c0], w1 = ea[c1], w2 = ea[c2], w3 = ea[c3];
      float v0 = __half2float(ha[(long long)c0 * 64 + lane]);
      float v1 = __half2float(ha[(long long)c1 * 64 + lane]);
      float v2 = __half2float(ha[(long long)c2 * 64 + lane]);
      float v3 = __half2float(ha[(long long)c3 * 64 + lane]);
      za += (w0 + w1) + (w2 + w3);
      aa += w0 * v0 + w1 * v1 + w2 * v2 + w3 * v3;
    }
    for (; p < p1; ++p) {
      int c = pool[p];
      float w = ea[c];
      za += w;
      aa += w * __half2float(ha[(long long)c * 64 + lane]);
    }
  }
  // head b, 4x unrolled
  float zb = 0.f, ab = 0.f;
  {
    int p0 = rp_b[row], p1 = rp_b[row + 1];
    int p = p0;
    for (; p + 4 <= p1; p += 4) {
      int c0 = pool[p + 0], c1 = pool[p + 1], c2 = pool[p + 2], c3 = pool[p + 3];
      float w0 = eb[c0], w1 = eb[c1], w2 = eb[c2], w3 = eb[c3];
      float v0 = __half2float(hb[(long long)c0 * 64 + lane]);
      float v1 = __half2float(hb[(long long)c1 * 64 + lane]);
      float v2 = __half2float(hb[(long long)c2 * 64 + lane]);
      float v3 = __half2float(hb[(long long)c3 * 64 + lane]);
      zb += (w0 + w1) + (w2 + w3);
      ab += w0 * v0 + w1 * v1 + w2 * v2 + w3 * v3;
    }
    for (; p < p1; ++p) {
      int c = pool[p];
      float w = eb[c];
      zb += w;
      ab += w * __half2float(hb[(long long)c * 64 + lane]);
    }
  }
  float r = (za > 0.f ? aa / za : 0.f) + (zb > 0.f ? ab / zb : 0.f);
  float pv = pw[0];
  r = r >= 0.f ? r : pv * r;          // H1 = prelu(...)
  // Tm = B2 @ H2t + trib (avg 1.5 entries/row; 2x unroll)
  float tm = trib[lane];
  {
    int p0 = rp_B2[row], p1 = rp_B2[row + 1];
    int p = p0;
    for (; p + 2 <= p1; p += 2) {
      int e0 = pool[p], e1 = pool[p + 1];
      int c0 = e0 / 3, c1 = e1 / 3;
      float s0 = (e0 - 3 * c0 == 1) ? -1.f : 1.f;
      float s1 = (e1 - 3 * c1 == 1) ? -1.f : 1.f;
      float v0 = __half2float(H2t[(long long)c0 * 64 + lane]);
      float v1 = __half2float(H2t[(long long)c1 * 64 + lane]);
      tm += s0 * v0 + s1 * v1;
    }
    for (; p < p1; ++p) {
      int e = pool[p];
      int c = e / 3;
      float s = (e - 3 * c == 1) ? -1.f : 1.f;
      tm += s * __half2float(H2t[(long long)c * 64 + lane]);
    }
  }
  G[(long long)row * 64 + lane] = __float2half(r + tm);
}

// ---------- out = (H0 + B1 @ G) / 3, B1 loop 4x unrolled ----------
__global__ __launch_bounds__(256) void final_kernel(
    const int* __restrict__ rowptr, const int* __restrict__ ent,
    const float* __restrict__ H0, const __half* __restrict__ G,
    float* __restrict__ out, int n) {
  int row = blockIdx.x * 4 + (threadIdx.x >> 6);
  if (row >= n) return;
  int lane = threadIdx.x & 63;
  int p0 = rowptr[row], p1 = rowptr[row + 1];
  float acc = H0[(long long)row * 64 + lane];
  int p = p0;
  for (; p + 4 <= p1; p += 4) {
    int e0 = ent[p], e1 = ent[p + 1], e2 = ent[p + 2], e3 = ent[p + 3];
    float s0 = (e0 & 1) ? -1.f : 1.f;
    float s1 = (e1 & 1) ? -1.f : 1.f;
    float s2 = (e2 & 1) ? -1.f : 1.f;
    float s3 = (e3 & 1) ? -1.f : 1.f;
    float v0 = __half2float(G[(long long)(e0 >> 1) * 64 + lane]);
    float v1 = __half2float(G[(long long)(e1 >> 1) * 64 + lane]);
    float v2 = __half2float(G[(long long)(e2 >> 1) * 64 + lane]);
    float v3 = __half2float(G[(long long)(e3 >> 1) * 64 + lane]);
    acc += s0 * v0 + s1 * v1 + s2 * v2 + s3 * v3;
  }
  for (; p < p1; ++p) {
    int e = ent[p];
    float s = (e & 1) ? -1.f : 1.f;
    acc += s * __half2float(G[(long long)(e >> 1) * 64 + lane]);
  }
  out[(long long)row * 64 + lane] = acc * (1.0f / 3.0f);
}

extern "C" void kernel_launch(void* const* d_in, const int* in_sizes, int n_in,
                              void* d_out, int out_size, void* d_ws, size_t ws_size,
                              hipStream_t stream) {
  const float* X0 = (const float*)d_in[0];
  const int* E1 = (const int*)d_in[1];
  const int* T2 = (const int*)d_in[2];
  const int* L0i = (const int*)d_in[3];
  const int* L1ai = (const int*)d_in[4];
  const int* L1bi = (const int*)d_in[5];
  const int* L2i = (const int*)d_in[6];
  const int* B1i = (const int*)d_in[7];
  const int* B2i = (const int*)d_in[9];
  const float* W = (const float*)d_in[11];
  const float* bvec = (const float*)d_in[12];
  // a1_w/a1_b are mathematically dead: s1[r] cancels in the row softmax.
  const float* a2w = (const float*)d_in[15];
  const float* a2b = (const float*)d_in[16];
  const float* pw = (const float*)d_in[17];
  const float* triW = (const float*)d_in[18];
  const float* trib = (const float*)d_in[19];
  float* out = (float*)d_out;

  char* base = (char*)d_ws;
  size_t off = 0;
  auto alloc = [&](size_t bytes) -> void* {
    void* p = base + off;
    off += (bytes + 255) & ~(size_t)255;
    return p;
  };
  unsigned int* Xbit = (unsigned int*)alloc((size_t)N0 * 16 * 4);
  unsigned short* Bp = (unsigned short*)alloc((size_t)3 * 65536 * 2);
  __half* Wt = (__half*)alloc((size_t)4096 * 2);
  __half* h0 = (__half*)alloc((size_t)N0 * 64 * 2);
  __half* h1 = (__half*)alloc((size_t)N0 * 64 * 2);
  __half* h2 = (__half*)alloc((size_t)N1 * 64 * 2);
  __half* h3 = (__half*)alloc((size_t)N1 * 64 * 2);
  __half* h4 = (__half*)alloc((size_t)N2 * 64 * 2);
  __half* h5 = (__half*)alloc((size_t)N2 * 64 * 2);
  float* e0 = (float*)alloc((size_t)N0 * 4);
  float* e1 = (float*)alloc((size_t)N0 * 4);
  float* e2 = (float*)alloc((size_t)N1 * 4);
  float* e3 = (float*)alloc((size_t)N1 * 4);
  float* e4 = (float*)alloc((size_t)N2 * 4);
  float* e5 = (float*)alloc((size_t)N2 * 4);
  float* H0 = (float*)alloc((size_t)N0 * 64 * 4);
  __half* H2 = (__half*)alloc((size_t)N2 * 64 * 2);
  __half* H2t = (__half*)alloc((size_t)N2 * 64 * 2);
  __half* G = (__half*)alloc((size_t)N1 * 64 * 2);
  int* gscan = (int*)alloc((size_t)(CNT_TOT + 1) * 4);
  int* pool = (int*)alloc((size_t)TOT_E * 4);
  int2* stage = (int2*)alloc((size_t)TOT_E * 8);
  int* bsum = (int*)alloc((size_t)(SCAN_BLOCKS + 1) * 4);
  int* zeroed = (int*)alloc((size_t)(CNT_TOT + NBUCK) * 4);   // cnt | bcur, one memset
  int* cnt = zeroed;
  int* bcur = zeroed + CNT_TOT;

  hipMemsetAsync(zeroed, 0, (size_t)(CNT_TOT + NBUCK) * 4, stream);

  pack_bits_kernel<<<(N0 + 3) / 4, 256, 0, stream>>>(X0, Xbit);
  pack_w_kernel<<<(3 * 65536 + 255) / 256, 256, 0, stream>>>(W, Bp);
  pack_wt_kernel<<<16, 256, 0, stream>>>(triW, Wt);

  gemm_sat_kernel<1><<<(N0 + 255) / 256, 256, 0, stream>>>(Xbit, nullptr, Bp, bvec, a2w, a2b, 0, N0, h0, h1, e0, e1);
  gemm_sat_kernel<2><<<(N1 + 255) / 256, 256, 0, stream>>>(Xbit, E1, Bp + 65536, bvec, a2w, a2b, 2, N1, h2, h3, e2, e3);
  gemm_sat_kernel<3><<<(N2 + 255) / 256, 256, 0, stream>>>(Xbit, T2, Bp + 2 * 65536, bvec, a2w, a2b, 4, N2, h4, h5, e4, e5);

  count_all_kernel<<<(TOT_E + 255) / 256, 256, 0, stream>>>(L0i, L1ai, L1bi, L2i, B1i, B2i, cnt);
  scan_partial_kernel<<<SCAN_BLOCKS, 256, 0, stream>>>(cnt, bsum);
  scan_bsum_kernel<<<1, 256, 0, stream>>>(bsum, SCAN_BLOCKS);
  scan_write_kernel<<<SCAN_BLOCKS, 256, 0, stream>>>(cnt, bsum, gscan);
  stage_all_kernel<<<(TOT_E + 255) / 256, 256, 0, stream>>>(L0i, L1ai, L1bi, L2i, B1i, B2i,
                                                            gscan, bcur, stage);
  fill_bucket_kernel<<<NBUCK, 256, 0, stream>>>(gscan, stage, pool);

  const int* rp0 = gscan + SEG_L0;
  const int* rp1a = gscan + SEG_L1A;
  const int* rp1b = gscan + SEG_L1B;
  const int* rp2 = gscan + SEG_L2;
  const int* rpB1 = gscan + SEG_B1;
  const int* rpB2 = gscan + SEG_B2;

  sat_dual_z_kernel<float><<<(N0 + 3) / 4, 256, 0, stream>>>(rp0, pool, e0, h0, e1, h1, pw, H0, N0);
  sat_dual_z_kernel<__half><<<(N2 + 3) / 4, 256, 0, stream>>>(rp2, pool, e4, h4, e5, h5, pw, H2, N2);
  tri_mfma_kernel<<<(N2 + 63) / 64, 256, 0, stream>>>(H2, Wt, H2t, N2);
  sat_l1_mega_kernel<<<(N1 + 3) / 4, 256, 0, stream>>>(rp1a, rp1b, rpB2, pool, e2, h2, e3, h3,
                                                       H2t, trib, pw, G, N1);
  final_kernel<<<(N0 + 3) / 4, 256, 0, stream>>>(rpB1, pool, H0, G, out, N0);
}

// Round 8
// 966.314 us; speedup vs baseline: 3.3310x; 3.3310x over previous
//
#include <hip/hip_runtime.h>
#include <hip/hip_fp16.h>

static constexpr int N0 = 50000;
static constexpr int N1 = 200000;
static constexpr int N2 = 100000;
static constexpr int NNZ0 = 600000;
static constexpr int NNZ1 = 1000000;
static constexpr int NNZ2 = 600000;
static constexpr int FIN = 500;

// concatenated count layout: [L0 | L1a | L1b | L2 | B1 | B2]
static constexpr int SEG_L0 = 0;
static constexpr int SEG_L1A = 50000;
static constexpr int SEG_L1B = 250000;
static constexpr int SEG_L2 = 450000;
static constexpr int SEG_B1 = 550000;
static constexpr int SEG_B2 = 600000;
static constexpr int CNT_TOT = 800000;
static constexpr int TOT_E = NNZ0 + NNZ1 + NNZ1 + NNZ2 + 2 * N1 + 3 * N2;  // 3.9M
static constexpr int SCAN_CHUNK = 4096;
static constexpr int SCAN_BLOCKS = (CNT_TOT + SCAN_CHUNK - 1) / SCAN_CHUNK;  // 196
// 32 rows/bucket: ~156 staged entries per bucket. Cursor padded to 1/cacheline:
// contention metric is atomic hits PER LINE (r7 post-mortem: 49 lines @80K hits = 2.5ms).
static constexpr int BUCK_SHIFT = 5;
static constexpr int NBUCK = CNT_TOT >> BUCK_SHIFT;   // 25000 (exact)
static constexpr int CUR_STRIDE = 16;                 // ints; 64 B per cursor

typedef __attribute__((ext_vector_type(8))) short bf16x8;
typedef __attribute__((ext_vector_type(8))) _Float16 f16x8;
typedef __attribute__((ext_vector_type(4))) float f32x4;

__device__ __forceinline__ unsigned short f2bf(float f) {
  unsigned int b = __float_as_uint(f);
  b = (b + 0x7FFFu + ((b >> 16) & 1u)) >> 16;   // RNE
  return (unsigned short)b;
}

// ---------- pack X0 -> binary bitmasks: 512 bits = 16 uints per row (3.2 MB, L2-resident) ----------
__global__ __launch_bounds__(256) void pack_bits_kernel(const float* __restrict__ X0,
                                                        unsigned int* __restrict__ Xbit) {
  int row = blockIdx.x * 4 + (threadIdx.x >> 6);
  if (row >= N0) return;
  int lane = threadIdx.x & 63;
  const float* xr = X0 + (long long)row * FIN;
#pragma unroll
  for (int i = 0; i < 8; ++i) {
    int c = i * 64 + lane;
    bool pred = (c < FIN) && (xr[c] != 0.0f);
    unsigned long long m = __ballot(pred);
    if (lane == 0) {
      Xbit[row * 16 + 2 * i] = (unsigned int)m;
      Xbit[row * 16 + 2 * i + 1] = (unsigned int)(m >> 32);
    }
  }
}

// ---------- pack W -> bf16 MFMA B-fragment layout: [level][kc][nb][lane][j] ----------
__global__ void pack_w_kernel(const float* __restrict__ W, unsigned short* __restrict__ Bp) {
  int g = blockIdx.x * 256 + threadIdx.x;
  if (g >= 3 * 65536) return;
  int j = g & 7;
  int lane = (g >> 3) & 63;
  int nb = (g >> 9) & 7;
  int kc = (g >> 12) & 15;
  int level = g >> 16;
  int k = kc * 32 + (lane >> 4) * 8 + j;
  int col128 = nb * 16 + (lane & 15);
  int head = level * 2 + (col128 >> 6);
  int col = col128 & 63;
  float f = 0.0f;
  if (k < FIN) f = W[((long long)head * FIN + k) * 64 + col];
  Bp[g] = f2bf(f);
}

// ---------- pack triW -> f16 B-fragment layout: [kc(2)][nb(4)][lane][j] ----------
__global__ void pack_wt_kernel(const float* __restrict__ triW, __half* __restrict__ Wt) {
  int g = blockIdx.x * 256 + threadIdx.x;
  if (g >= 4096) return;
  int j = g & 7;
  int lane = (g >> 3) & 63;
  int nb = (g >> 9) & 3;
  int kc = g >> 11;
  int k = kc * 32 + (lane >> 4) * 8 + j;
  int col = nb * 16 + (lane & 15);
  Wt[g] = __float2half(triW[k * 64 + col]);
}

// ---------- fused bit-gather(AND) + in-register bf16 expansion + MFMA ----------
template <int NSRC>
__global__ __launch_bounds__(256) void gemm_sat_kernel(
    const unsigned int* __restrict__ Xbit, const int* __restrict__ srcidx,
    const unsigned short* __restrict__ Bp, const float* __restrict__ bvec,
    const float* __restrict__ a2w, const float* __restrict__ a2b, int head_lo,
    int M, __half* __restrict__ h_lo, __half* __restrict__ h_hi,
    float* __restrict__ e_lo, float* __restrict__ e_hi) {
  __shared__ __align__(16) unsigned int Sb[256 * 20];
  const int tid = threadIdx.x;
  const int m0 = blockIdx.x * 256;
  {
    int rg = m0 + tid;
    uint4 a[4];
#pragma unroll
    for (int c = 0; c < 4; ++c) a[c] = make_uint4(0u, 0u, 0u, 0u);
    if (rg < M) {
      if (NSRC == 1) {
        const uint4* up = (const uint4*)(Xbit + (long long)rg * 16);
#pragma unroll
        for (int c = 0; c < 4; ++c) a[c] = up[c];
      } else if (NSRC == 2) {
        const uint4* up = (const uint4*)(Xbit + (long long)srcidx[2 * rg + 0] * 16);
        const uint4* vp = (const uint4*)(Xbit + (long long)srcidx[2 * rg + 1] * 16);
#pragma unroll
        for (int c = 0; c < 4; ++c) {
          uint4 u = up[c], v = vp[c];
          a[c] = make_uint4(u.x & v.x, u.y & v.y, u.z & v.z, u.w & v.w);
        }
      } else {
        const uint4* up = (const uint4*)(Xbit + (long long)srcidx[3 * rg + 0] * 16);
        const uint4* vp = (const uint4*)(Xbit + (long long)srcidx[3 * rg + 1] * 16);
        const uint4* wp = (const uint4*)(Xbit + (long long)srcidx[3 * rg + 2] * 16);
#pragma unroll
        for (int c = 0; c < 4; ++c) {
          uint4 u = up[c], v = vp[c], w = wp[c];
          a[c] = make_uint4(u.x & v.x & w.x, u.y & v.y & w.y, u.z & v.z & w.z, u.w & v.w & w.w);
        }
      }
    }
#pragma unroll
    for (int c = 0; c < 4; ++c) *(uint4*)(Sb + tid * 20 + c * 4) = a[c];
  }
  __syncthreads();

  const int wave = tid >> 6;
  const int lane = tid & 63;
  const int quad = lane >> 4;
  const int l16 = lane & 15;
  f32x4 acc[8][4];   // [nb][sub]
#pragma unroll
  for (int i = 0; i < 8; ++i)
#pragma unroll
    for (int s = 0; s < 4; ++s) acc[i][s] = (f32x4){0.f, 0.f, 0.f, 0.f};
  const bf16x8* Bf = (const bf16x8*)Bp;
#pragma unroll 2
  for (int kc = 0; kc < 16; ++kc) {
    bf16x8 af[4];
#pragma unroll
    for (int sub = 0; sub < 4; ++sub) {
      unsigned int bw = Sb[(wave * 64 + sub * 16 + l16) * 20 + kc];
      unsigned int byte = (bw >> (quad * 8)) & 0xFFu;
#pragma unroll
      for (int j = 0; j < 4; ++j) {
        unsigned int b2 = (byte >> (2 * j)) & 3u;
        ((unsigned int*)&af[sub])[j] = ((b2 & 1u) | ((b2 & 2u) << 15)) * 0x3F80u;
      }
    }
#pragma unroll
    for (int nb = 0; nb < 8; ++nb) {
      bf16x8 bf = Bf[(kc * 8 + nb) * 64 + lane];
#pragma unroll
      for (int sub = 0; sub < 4; ++sub)
        acc[nb][sub] = __builtin_amdgcn_mfma_f32_16x16x32_bf16(af[sub], bf, acc[nb][sub], 0, 0, 0);
    }
  }

  float bia[8], aw[8];
#pragma unroll
  for (int nb = 0; nb < 8; ++nb) {
    int col128 = nb * 16 + l16;
    int hh = col128 >> 6, col = col128 & 63;
    bia[nb] = bvec[(head_lo + hh) * 64 + col];
    aw[nb] = a2w[(head_lo + hh) * 64 + col];
  }
  float blo = a2b[head_lo], bhi = a2b[head_lo + 1];
#pragma unroll
  for (int sub = 0; sub < 4; ++sub) {
    float plo[4] = {0.f, 0.f, 0.f, 0.f};
    float phi[4] = {0.f, 0.f, 0.f, 0.f};
#pragma unroll
    for (int nb = 0; nb < 8; ++nb) {
      int col128 = nb * 16 + l16;
      int hh = col128 >> 6, col = col128 & 63;
      __half* hdst = hh ? h_hi : h_lo;
#pragma unroll
      for (int reg = 0; reg < 4; ++reg) {
        int rg = m0 + wave * 64 + sub * 16 + quad * 4 + reg;   // C/D: row=quad*4+reg, col=l16
        float v = acc[nb][sub][reg] + bia[nb];
        if (rg < M) hdst[(long long)rg * 64 + col] = __float2half(v);
        if (hh) phi[reg] += v * aw[nb]; else plo[reg] += v * aw[nb];
      }
    }
#pragma unroll
    for (int off = 1; off < 16; off <<= 1) {
#pragma unroll
      for (int reg = 0; reg < 4; ++reg) {
        plo[reg] += __shfl_xor(plo[reg], off);
        phi[reg] += __shfl_xor(phi[reg], off);
      }
    }
    if (l16 == 0) {
#pragma unroll
      for (int reg = 0; reg < 4; ++reg) {
        int rg = m0 + wave * 64 + sub * 16 + quad * 4 + reg;
        if (rg < M) {
          e_lo[rg] = __expf(plo[reg] + blo);   // |s2| small by construction: no max needed
          e_hi[rg] = __expf(phi[reg] + bhi);
        }
      }
    }
  }
}

// ---------- merged CSR build ----------
__global__ __launch_bounds__(256) void count_all_kernel(
    const int* __restrict__ r0, const int* __restrict__ r1a, const int* __restrict__ r1b,
    const int* __restrict__ r2, const int* __restrict__ rb1, const int* __restrict__ rb2,
    int* __restrict__ cnt) {
  int g = blockIdx.x * 256 + threadIdx.x;
  if (g >= TOT_E) return;
  int seg, r;
  if (g < 600000) { seg = SEG_L0; r = r0[g]; }
  else if (g < 1600000) { seg = SEG_L1A; r = r1a[g - 600000]; }
  else if (g < 2600000) { seg = SEG_L1B; r = r1b[g - 1600000]; }
  else if (g < 3200000) { seg = SEG_L2; r = r2[g - 2600000]; }
  else if (g < 3600000) { seg = SEG_B1; r = rb1[g - 3200000]; }
  else { seg = SEG_B2; r = rb2[g - 3600000]; }
  atomicAdd(&cnt[seg + r], 1);
}

__global__ __launch_bounds__(256) void scan_partial_kernel(const int* __restrict__ cnt,
                                                           int* __restrict__ bsum) {
  __shared__ int s[256];
  int b = blockIdx.x, t = threadIdx.x;
  int base = b * SCAN_CHUNK + t * 16;
  int sum = 0;
#pragma unroll
  for (int i = 0; i < 16; ++i) {
    int idx = base + i;
    if (idx < CNT_TOT) sum += cnt[idx];
  }
  s[t] = sum;
  __syncthreads();
  for (int off = 128; off > 0; off >>= 1) {
    if (t < off) s[t] += s[t + off];
    __syncthreads();
  }
  if (t == 0) bsum[b] = s[0];
}

__global__ __launch_bounds__(256) void scan_bsum_kernel(int* __restrict__ bsum, int nb) {
  __shared__ int s[256];
  int t = threadIdx.x;
  int v = (t < nb) ? bsum[t] : 0;
  s[t] = v;
  __syncthreads();
  for (int off = 1; off < 256; off <<= 1) {
    int u = (t >= off) ? s[t - off] : 0;
    __syncthreads();
    s[t] += u;
    __syncthreads();
  }
  if (t < nb) bsum[t] = (t == 0) ? 0 : s[t - 1];
  if (t == 0) bsum[nb] = s[nb - 1];
}

__global__ __launch_bounds__(256) void scan_write_kernel(const int* __restrict__ cnt,
                                                         const int* __restrict__ bsum,
                                                         int* __restrict__ gscan) {
  __shared__ int s[256];
  int b = blockIdx.x, t = threadIdx.x;
  int base = b * SCAN_CHUNK + t * 16;
  int loc[16];
  int sum = 0;
#pragma unroll
  for (int i = 0; i < 16; ++i) {
    int idx = base + i;
    int v = (idx < CNT_TOT) ? cnt[idx] : 0;
    loc[i] = sum;
    sum += v;
  }
  s[t] = sum;
  __syncthreads();
  for (int off = 1; off < 256; off <<= 1) {
    int u = (t >= off) ? s[t - off] : 0;
    __syncthreads();
    s[t] += u;
    __syncthreads();
  }
  int toff = bsum[b] + ((t == 0) ? 0 : s[t - 1]);
#pragma unroll
  for (int i = 0; i < 16; ++i) {
    int idx = base + i;
    if (idx < CNT_TOT) gscan[idx] = toff + loc[i];
  }
  if (b == 0 && t == 0) gscan[CNT_TOT] = bsum[SCAN_BLOCKS];
}

// ---------- pass A: append (row,val) into bucket-contiguous staging (dense, clustered writes) ----------
__global__ __launch_bounds__(256) void stage_all_kernel(
    const int* __restrict__ r0, const int* __restrict__ r1a, const int* __restrict__ r1b,
    const int* __restrict__ r2, const int* __restrict__ rb1, const int* __restrict__ rb2,
    const int* __restrict__ gscan, int* __restrict__ bcur, int2* __restrict__ stage) {
  int g = blockIdx.x * 256 + threadIdx.x;
  if (g >= TOT_E) return;
  int seg, r, val;
  if (g < 600000) { int l = g; seg = SEG_L0; r = r0[l]; val = r0[NNZ0 + l]; }
  else if (g < 1600000) { int l = g - 600000; seg = SEG_L1A; r = r1a[l]; val = r1a[NNZ1 + l]; }
  else if (g < 2600000) { int l = g - 1600000; seg = SEG_L1B; r = r1b[l]; val = r1b[NNZ1 + l]; }
  else if (g < 3200000) { int l = g - 2600000; seg = SEG_L2; r = r2[l]; val = r2[NNZ2 + l]; }
  else if (g < 3600000) { int l = g - 3200000; seg = SEG_B1; r = rb1[l]; val = l; }
  else { int l = g - 3600000; seg = SEG_B2; r = rb2[l]; val = l; }
  int row = seg + r;
  int b = row >> BUCK_SHIFT;
  int pos = gscan[b << BUCK_SHIFT] + atomicAdd(&bcur[b * CUR_STRIDE], 1);  // 1 cursor/line
  stage[pos] = make_int2(row, val);
}

// ---------- pass B: one bucket per WAVE (4/block); LDS cursors; scatter within ~0.6KB slice ----------
__global__ __launch_bounds__(256) void fill_bucket_kernel(
    const int* __restrict__ gscan, const int2* __restrict__ stage, int* __restrict__ pool) {
  __shared__ int lcur[4][1 << BUCK_SHIFT];
  int wave = threadIdx.x >> 6;
  int lane = threadIdx.x & 63;
  int b = blockIdx.x * 4 + wave;          // NBUCK = 25000 = gridDim 6250 * 4 exactly
  if (lane < (1 << BUCK_SHIFT)) lcur[wave][lane] = 0;
  __syncthreads();
  int base_row = b << BUCK_SHIFT;
  int start = gscan[base_row], end = gscan[base_row + (1 << BUCK_SHIFT)];
  for (int i = start + lane; i < end; i += 64) {
    int2 rv = stage[i];
    int pos = gscan[rv.x] + atomicAdd(&lcur[wave][rv.x & ((1 << BUCK_SHIFT) - 1)], 1);
    pool[pos] = rv.y;
  }
}

// ---------- dual-table gather over one CSR row, 4x unrolled for MLP ----------
__device__ __forceinline__ void dual_gather_row(
    const int* __restrict__ col, int p0, int p1, int lane,
    const float* __restrict__ ea, const __half* __restrict__ ha,
    const float* __restrict__ eb, const __half* __restrict__ hb,
    float& za, float& aa, float& zb, float& ab) {
  int p = p0;
  for (; p + 4 <= p1; p += 4) {
    int c0 = col[p + 0], c1 = col[p + 1], c2 = col[p + 2], c3 = col[p + 3];
    float wa0 = ea[c0], wa1 = ea[c1], wa2 = ea[c2], wa3 = ea[c3];
    float wb0 = eb[c0], wb1 = eb[c1], wb2 = eb[c2], wb3 = eb[c3];
    float va0 = __half2float(ha[(long long)c0 * 64 + lane]);
    float va1 = __half2float(ha[(long long)c1 * 64 + lane]);
    float va2 = __half2float(ha[(long long)c2 * 64 + lane]);
    float va3 = __half2float(ha[(long long)c3 * 64 + lane]);
    float vb0 = __half2float(hb[(long long)c0 * 64 + lane]);
    float vb1 = __half2float(hb[(long long)c1 * 64 + lane]);
    float vb2 = __half2float(hb[(long long)c2 * 64 + lane]);
    float vb3 = __half2float(hb[(long long)c3 * 64 + lane]);
    za += (wa0 + wa1) + (wa2 + wa3);
    zb += (wb0 + wb1) + (wb2 + wb3);
    aa += wa0 * va0 + wa1 * va1 + wa2 * va2 + wa3 * va3;
    ab += wb0 * vb0 + wb1 * vb1 + wb2 * vb2 + wb3 * vb3;
  }
  for (; p < p1; ++p) {
    int c = col[p];
    float wa = ea[c], wb = eb[c];
    za += wa; zb += wb;
    aa += wa * __half2float(ha[(long long)c * 64 + lane]);
    ab += wb * __half2float(hb[(long long)c * 64 + lane]);
  }
}

// ---------- SAT dual (L0, L2): one traversal, expv precomputed per node ----------
template <typename OutT>
__global__ __launch_bounds__(256) void sat_dual_z_kernel(
    const int* __restrict__ rowptr, const int* __restrict__ col,
    const float* __restrict__ ea, const __half* __restrict__ ha,
    const float* __restrict__ eb, const __half* __restrict__ hb,
    const float* __restrict__ pw, OutT* __restrict__ out, int n) {
  int row = blockIdx.x * 4 + (threadIdx.x >> 6);
  if (row >= n) return;
  int lane = threadIdx.x & 63;
  int p0 = rowptr[row], p1 = rowptr[row + 1];
  float za = 0.f, zb = 0.f, aa = 0.f, ab = 0.f;
  dual_gather_row(col, p0, p1, lane, ea, ha, eb, hb, za, aa, zb, ab);
  float r = (za > 0.f ? aa / za : 0.f) + (zb > 0.f ? ab / zb : 0.f);
  float pv = pw[0];
  r = r >= 0.f ? r : pv * r;   // prelu
  out[(long long)row * 64 + lane] = (OutT)r;
}

// ---------- H2t = H2 @ triW via f16 MFMA ----------
__global__ __launch_bounds__(256) void tri_mfma_kernel(
    const __half* __restrict__ H2, const __half* __restrict__ Wt,
    __half* __restrict__ H2t, int n) {
  const int tid = threadIdx.x;
  const int m0 = blockIdx.x * 64;
  const int wave = tid >> 6;
  const int lane = tid & 63;
  const int quad = lane >> 4;
  const int l16 = lane & 15;
  const int arow = m0 + wave * 16 + l16;
  f32x4 acc[4];
#pragma unroll
  for (int i = 0; i < 4; ++i) acc[i] = (f32x4){0.f, 0.f, 0.f, 0.f};
  const f16x8* Wf = (const f16x8*)Wt;
#pragma unroll
  for (int kc = 0; kc < 2; ++kc) {
    f16x8 af = (f16x8){0, 0, 0, 0, 0, 0, 0, 0};
    if (arow < n) af = *(const f16x8*)((const _Float16*)H2 + (long long)arow * 64 + kc * 32 + quad * 8);
#pragma unroll
    for (int nb = 0; nb < 4; ++nb) {
      f16x8 bf = Wf[(kc * 4 + nb) * 64 + lane];
      acc[nb] = __builtin_amdgcn_mfma_f32_16x16x32_f16(af, bf, acc[nb], 0, 0, 0);
    }
  }
#pragma unroll
  for (int nb = 0; nb < 4; ++nb) {
    int col = nb * 16 + l16;
#pragma unroll
    for (int reg = 0; reg < 4; ++reg) {
      int rg = m0 + wave * 16 + quad * 4 + reg;
      if (rg < n) H2t[(long long)rg * 64 + col] = __float2half(acc[nb][reg]);
    }
  }
}

// ---------- mega edge-row kernel: G = prelu(satL1a + satL1b) + trib + B2 @ H2t ----------
__global__ __launch_bounds__(256) void sat_l1_mega_kernel(
    const int* __restrict__ rp_a, const int* __restrict__ rp_b, const int* __restrict__ rp_B2,
    const int* __restrict__ pool,
    const float* __restrict__ ea, const __half* __restrict__ ha,
    const float* __restrict__ eb, const __half* __restrict__ hb,
    const __half* __restrict__ H2t, const float* __restrict__ trib,
    const float* __restrict__ pw, __half* __restrict__ G, int n) {
  int row = blockIdx.x * 4 + (threadIdx.x >> 6);
  if (row >= n) return;
  int lane = threadIdx.x & 63;
  // head a, 4x unrolled
  float za = 0.f, aa = 0.f;
  {
    int p0 = rp_a[row], p1 = rp_a[row + 1];
    int p = p0;
    for (; p + 4 <= p1; p += 4) {
      int c0 = pool[p + 0], c1 = pool[p + 1], c2 = pool[p + 2], c3 = pool[p + 3];
      float w0 = ea[c0], w1 = ea[c1], w2 = ea[c2], w3 = ea[c3];
      float v0 = __half2float(ha[(long long)c0 * 64 + lane]);
      float v1 = __half2float(ha[(long long)c1 * 64 + lane]);
      float v2 = __half2float(ha[(long long)c2 * 64 + lane]);
      float v3 = __half2float(ha[(long long)c3 * 64 + lane]);
      za += (w0 + w1) + (w2 + w3);
      aa += w0 * v0 + w1 * v1 + w2 * v2 + w3 * v3;
    }
    for (; p < p1; ++p) {
      int c = pool[p];
      float w = ea[c];
      za += w;
      aa += w * __half2float(ha[(long long)c * 64 + lane]);
    }
  }
  // head b, 4x unrolled
  float zb = 0.f, ab = 0.f;
  {
    int p0 = rp_b[row], p1 = rp_b[row + 1];
    int p = p0;
    for (; p + 4 <= p1; p += 4) {
      int c0 = pool[p + 0], c1 = pool[p + 1], c2 = pool[p + 2], c3 = pool[p + 3];
      float w0 = eb[c0], w1 = eb[c1], w2 = eb[c2], w3 = eb[c3];
      float v0 = __half2float(hb[(long long)c0 * 64 + lane]);
      float v1 = __half2float(hb[(long long)c1 * 64 + lane]);
      float v2 = __half2float(hb[(long long)c2 * 64 + lane]);
      float v3 = __half2float(hb[(long long)c3 * 64 + lane]);
      zb += (w0 + w1) + (w2 + w3);
      ab += w0 * v0 + w1 * v1 + w2 * v2 + w3 * v3;
    }
    for (; p < p1; ++p) {
      int c = pool[p];
      float w = eb[c];
      zb += w;
      ab += w * __half2float(hb[(long long)c * 64 + lane]);
    }
  }
  float r = (za > 0.f ? aa / za : 0.f) + (zb > 0.f ? ab / zb : 0.f);
  float pv = pw[0];
  r = r >= 0.f ? r : pv * r;          // H1 = prelu(...)
  // Tm = B2 @ H2t + trib (avg 1.5 entries/row; 2x unroll)
  float tm = trib[lane];
  {
    int p0 = rp_B2[row], p1 = rp_B2[row + 1];
    int p = p0;
    for (; p + 2 <= p1; p += 2) {
      int e0 = pool[p], e1 = pool[p + 1];
      int c0 = e0 / 3, c1 = e1 / 3;
      float s0 = (e0 - 3 * c0 == 1) ? -1.f : 1.f;
      float s1 = (e1 - 3 * c1 == 1) ? -1.f : 1.f;
      float v0 = __half2float(H2t[(long long)c0 * 64 + lane]);
      float v1 = __half2float(H2t[(long long)c1 * 64 + lane]);
      tm += s0 * v0 + s1 * v1;
    }
    for (; p < p1; ++p) {
      int e = pool[p];
      int c = e / 3;
      float s = (e - 3 * c == 1) ? -1.f : 1.f;
      tm += s * __half2float(H2t[(long long)c * 64 + lane]);
    }
  }
  G[(long long)row * 64 + lane] = __float2half(r + tm);
}

// ---------- out = (H0 + B1 @ G) / 3, B1 loop 4x unrolled ----------
__global__ __launch_bounds__(256) void final_kernel(
    const int* __restrict__ rowptr, const int* __restrict__ ent,
    const float* __restrict__ H0, const __half* __restrict__ G,
    float* __restrict__ out, int n) {
  int row = blockIdx.x * 4 + (threadIdx.x >> 6);
  if (row >= n) return;
  int lane = threadIdx.x & 63;
  int p0 = rowptr[row], p1 = rowptr[row + 1];
  float acc = H0[(long long)row * 64 + lane];
  int p = p0;
  for (; p + 4 <= p1; p += 4) {
    int e0 = ent[p], e1 = ent[p + 1], e2 = ent[p + 2], e3 = ent[p + 3];
    float s0 = (e0 & 1) ? -1.f : 1.f;
    float s1 = (e1 & 1) ? -1.f : 1.f;
    float s2 = (e2 & 1) ? -1.f : 1.f;
    float s3 = (e3 & 1) ? -1.f : 1.f;
    float v0 = __half2float(G[(long long)(e0 >> 1) * 64 + lane]);
    float v1 = __half2float(G[(long long)(e1 >> 1) * 64 + lane]);
    float v2 = __half2float(G[(long long)(e2 >> 1) * 64 + lane]);
    float v3 = __half2float(G[(long long)(e3 >> 1) * 64 + lane]);
    acc += s0 * v0 + s1 * v1 + s2 * v2 + s3 * v3;
  }
  for (; p < p1; ++p) {
    int e = ent[p];
    float s = (e & 1) ? -1.f : 1.f;
    acc += s * __half2float(G[(long long)(e >> 1) * 64 + lane]);
  }
  out[(long long)row * 64 + lane] = acc * (1.0f / 3.0f);
}

extern "C" void kernel_launch(void* const* d_in, const int* in_sizes, int n_in,
                              void* d_out, int out_size, void* d_ws, size_t ws_size,
                              hipStream_t stream) {
  const float* X0 = (const float*)d_in[0];
  const int* E1 = (const int*)d_in[1];
  const int* T2 = (const int*)d_in[2];
  const int* L0i = (const int*)d_in[3];
  const int* L1ai = (const int*)d_in[4];
  const int* L1bi = (const int*)d_in[5];
  const int* L2i = (const int*)d_in[6];
  const int* B1i = (const int*)d_in[7];
  const int* B2i = (const int*)d_in[9];
  const float* W = (const float*)d_in[11];
  const float* bvec = (const float*)d_in[12];
  // a1_w/a1_b are mathematically dead: s1[r] cancels in the row softmax.
  const float* a2w = (const float*)d_in[15];
  const float* a2b = (const float*)d_in[16];
  const float* pw = (const float*)d_in[17];
  const float* triW = (const float*)d_in[18];
  const float* trib = (const float*)d_in[19];
  float* out = (float*)d_out;

  char* base = (char*)d_ws;
  size_t off = 0;
  auto alloc = [&](size_t bytes) -> void* {
    void* p = base + off;
    off += (bytes + 255) & ~(size_t)255;
    return p;
  };
  unsigned int* Xbit = (unsigned int*)alloc((size_t)N0 * 16 * 4);
  unsigned short* Bp = (unsigned short*)alloc((size_t)3 * 65536 * 2);
  __half* Wt = (__half*)alloc((size_t)4096 * 2);
  __half* h0 = (__half*)alloc((size_t)N0 * 64 * 2);
  __half* h1 = (__half*)alloc((size_t)N0 * 64 * 2);
  __half* h2 = (__half*)alloc((size_t)N1 * 64 * 2);
  __half* h3 = (__half*)alloc((size_t)N1 * 64 * 2);
  __half* h4 = (__half*)alloc((size_t)N2 * 64 * 2);
  __half* h5 = (__half*)alloc((size_t)N2 * 64 * 2);
  float* e0 = (float*)alloc((size_t)N0 * 4);
  float* e1 = (float*)alloc((size_t)N0 * 4);
  float* e2 = (float*)alloc((size_t)N1 * 4);
  float* e3 = (float*)alloc((size_t)N1 * 4);
  float* e4 = (float*)alloc((size_t)N2 * 4);
  float* e5 = (float*)alloc((size_t)N2 * 4);
  float* H0 = (float*)alloc((size_t)N0 * 64 * 4);
  __half* H2 = (__half*)alloc((size_t)N2 * 64 * 2);
  __half* H2t = (__half*)alloc((size_t)N2 * 64 * 2);
  __half* G = (__half*)alloc((size_t)N1 * 64 * 2);
  int* gscan = (int*)alloc((size_t)(CNT_TOT + 1) * 4);
  int* pool = (int*)alloc((size_t)TOT_E * 4);
  int2* stage = (int2*)alloc((size_t)TOT_E * 8);
  int* bsum = (int*)alloc((size_t)(SCAN_BLOCKS + 1) * 4);
  int* zeroed = (int*)alloc((size_t)(CNT_TOT + NBUCK * CUR_STRIDE) * 4);   // cnt | bcur
  int* cnt = zeroed;
  int* bcur = zeroed + CNT_TOT;

  hipMemsetAsync(zeroed, 0, (size_t)(CNT_TOT + NBUCK * CUR_STRIDE) * 4, stream);

  pack_bits_kernel<<<(N0 + 3) / 4, 256, 0, stream>>>(X0, Xbit);
  pack_w_kernel<<<(3 * 65536 + 255) / 256, 256, 0, stream>>>(W, Bp);
  pack_wt_kernel<<<16, 256, 0, stream>>>(triW, Wt);

  gemm_sat_kernel<1><<<(N0 + 255) / 256, 256, 0, stream>>>(Xbit, nullptr, Bp, bvec, a2w, a2b, 0, N0, h0, h1, e0, e1);
  gemm_sat_kernel<2><<<(N1 + 255) / 256, 256, 0, stream>>>(Xbit, E1, Bp + 65536, bvec, a2w, a2b, 2, N1, h2, h3, e2, e3);
  gemm_sat_kernel<3><<<(N2 + 255) / 256, 256, 0, stream>>>(Xbit, T2, Bp + 2 * 65536, bvec, a2w, a2b, 4, N2, h4, h5, e4, e5);

  count_all_kernel<<<(TOT_E + 255) / 256, 256, 0, stream>>>(L0i, L1ai, L1bi, L2i, B1i, B2i, cnt);
  scan_partial_kernel<<<SCAN_BLOCKS, 256, 0, stream>>>(cnt, bsum);
  scan_bsum_kernel<<<1, 256, 0, stream>>>(bsum, SCAN_BLOCKS);
  scan_write_kernel<<<SCAN_BLOCKS, 256, 0, stream>>>(cnt, bsum, gscan);
  stage_all_kernel<<<(TOT_E + 255) / 256, 256, 0, stream>>>(L0i, L1ai, L1bi, L2i, B1i, B2i,
                                                            gscan, bcur, stage);
  fill_bucket_kernel<<<NBUCK / 4, 256, 0, stream>>>(gscan, stage, pool);

  const int* rp0 = gscan + SEG_L0;
  const int* rp1a = gscan + SEG_L1A;
  const int* rp1b = gscan + SEG_L1B;
  const int* rp2 = gscan + SEG_L2;
  const int* rpB1 = gscan + SEG_B1;
  const int* rpB2 = gscan + SEG_B2;

  sat_dual_z_kernel<float><<<(N0 + 3) / 4, 256, 0, stream>>>(rp0, pool, e0, h0, e1, h1, pw, H0, N0);
  sat_dual_z_kernel<__half><<<(N2 + 3) / 4, 256, 0, stream>>>(rp2, pool, e4, h4, e5, h5, pw, H2, N2);
  tri_mfma_kernel<<<(N2 + 63) / 64, 256, 0, stream>>>(H2, Wt, H2t, N2);
  sat_l1_mega_kernel<<<(N1 + 3) / 4, 256, 0, stream>>>(rp1a, rp1b, rpB2, pool, e2, h2, e3, h3,
                                                       H2t, trib, pw, G, N1);
  final_kernel<<<(N0 + 3) / 4, 256, 0, stream>>>(rpB1, pool, H0, G, out, N0);
}

// Round 9
// 780.446 us; speedup vs baseline: 4.1244x; 1.2382x over previous
//
#include <hip/hip_runtime.h>
#include <hip/hip_fp16.h>

static constexpr int N0 = 50000;
static constexpr int N1 = 200000;
static constexpr int N2 = 100000;
static constexpr int NNZ0 = 600000;
static constexpr int NNZ1 = 1000000;
static constexpr int NNZ2 = 600000;
static constexpr int FIN = 500;

// concatenated count layout: [L0 | L1a | L1b | L2 | B1 | B2]
static constexpr int SEG_L0 = 0;
static constexpr int SEG_L1A = 50000;
static constexpr int SEG_L1B = 250000;
static constexpr int SEG_L2 = 450000;
static constexpr int SEG_B1 = 550000;
static constexpr int SEG_B2 = 600000;
static constexpr int CNT_TOT = 800000;
static constexpr int TOT_E = NNZ0 + NNZ1 + NNZ1 + NNZ2 + 2 * N1 + 3 * N2;  // 3.9M
// radix partition: 256 partition blocks x 391 coarse buckets (2048 rows each).
// Every stage run and every pool slice is written by exactly ONE block ->
// no cross-XCD partial-line writes (r8 post-mortem: 225MB HBM writes for 31MB data).
static constexpr int NBLK = 256;
static constexpr int EPB = (TOT_E + NBLK - 1) / NBLK;        // 15235 entries/block
static constexpr int CB_SHIFT = 11;                          // 2048 rows per coarse bucket
static constexpr int CB = (CNT_TOT + (1 << CB_SHIFT) - 1) >> CB_SHIFT;  // 391
static constexpr int BH_N = CB * NBLK;                       // 100096
static constexpr int SCAN_CHUNK = 4096;
static constexpr int BH_SCAN_BLOCKS = (BH_N + SCAN_CHUNK - 1) / SCAN_CHUNK;  // 25

typedef __attribute__((ext_vector_type(8))) short bf16x8;
typedef __attribute__((ext_vector_type(8))) _Float16 f16x8;
typedef __attribute__((ext_vector_type(4))) float f32x4;

__device__ __forceinline__ unsigned short f2bf(float f) {
  unsigned int b = __float_as_uint(f);
  b = (b + 0x7FFFu + ((b >> 16) & 1u)) >> 16;   // RNE
  return (unsigned short)b;
}

// ---------- pack X0 -> binary bitmasks: 512 bits = 16 uints per row (3.2 MB, L2-resident) ----------
__global__ __launch_bounds__(256) void pack_bits_kernel(const float* __restrict__ X0,
                                                        unsigned int* __restrict__ Xbit) {
  int row = blockIdx.x * 4 + (threadIdx.x >> 6);
  if (row >= N0) return;
  int lane = threadIdx.x & 63;
  const float* xr = X0 + (long long)row * FIN;
#pragma unroll
  for (int i = 0; i < 8; ++i) {
    int c = i * 64 + lane;
    bool pred = (c < FIN) && (xr[c] != 0.0f);
    unsigned long long m = __ballot(pred);
    if (lane == 0) {
      Xbit[row * 16 + 2 * i] = (unsigned int)m;
      Xbit[row * 16 + 2 * i + 1] = (unsigned int)(m >> 32);
    }
  }
}

// ---------- pack W -> bf16 MFMA B-fragment layout: [level][kc][nb][lane][j] ----------
__global__ void pack_w_kernel(const float* __restrict__ W, unsigned short* __restrict__ Bp) {
  int g = blockIdx.x * 256 + threadIdx.x;
  if (g >= 3 * 65536) return;
  int j = g & 7;
  int lane = (g >> 3) & 63;
  int nb = (g >> 9) & 7;
  int kc = (g >> 12) & 15;
  int level = g >> 16;
  int k = kc * 32 + (lane >> 4) * 8 + j;
  int col128 = nb * 16 + (lane & 15);
  int head = level * 2 + (col128 >> 6);
  int col = col128 & 63;
  float f = 0.0f;
  if (k < FIN) f = W[((long long)head * FIN + k) * 64 + col];
  Bp[g] = f2bf(f);
}

// ---------- pack triW -> f16 B-fragment layout: [kc(2)][nb(4)][lane][j] ----------
__global__ void pack_wt_kernel(const float* __restrict__ triW, __half* __restrict__ Wt) {
  int g = blockIdx.x * 256 + threadIdx.x;
  if (g >= 4096) return;
  int j = g & 7;
  int lane = (g >> 3) & 63;
  int nb = (g >> 9) & 3;
  int kc = g >> 11;
  int k = kc * 32 + (lane >> 4) * 8 + j;
  int col = nb * 16 + (lane & 15);
  Wt[g] = __float2half(triW[k * 64 + col]);
}

// ---------- fused bit-gather(AND) + in-register bf16 expansion + MFMA ----------
template <int NSRC>
__global__ __launch_bounds__(256) void gemm_sat_kernel(
    const unsigned int* __restrict__ Xbit, const int* __restrict__ srcidx,
    const unsigned short* __restrict__ Bp, const float* __restrict__ bvec,
    const float* __restrict__ a2w, const float* __restrict__ a2b, int head_lo,
    int M, __half* __restrict__ h_lo, __half* __restrict__ h_hi,
    float* __restrict__ e_lo, float* __restrict__ e_hi) {
  __shared__ __align__(16) unsigned int Sb[256 * 20];
  const int tid = threadIdx.x;
  const int m0 = blockIdx.x * 256;
  {
    int rg = m0 + tid;
    uint4 a[4];
#pragma unroll
    for (int c = 0; c < 4; ++c) a[c] = make_uint4(0u, 0u, 0u, 0u);
    if (rg < M) {
      if (NSRC == 1) {
        const uint4* up = (const uint4*)(Xbit + (long long)rg * 16);
#pragma unroll
        for (int c = 0; c < 4; ++c) a[c] = up[c];
      } else if (NSRC == 2) {
        const uint4* up = (const uint4*)(Xbit + (long long)srcidx[2 * rg + 0] * 16);
        const uint4* vp = (const uint4*)(Xbit + (long long)srcidx[2 * rg + 1] * 16);
#pragma unroll
        for (int c = 0; c < 4; ++c) {
          uint4 u = up[c], v = vp[c];
          a[c] = make_uint4(u.x & v.x, u.y & v.y, u.z & v.z, u.w & v.w);
        }
      } else {
        const uint4* up = (const uint4*)(Xbit + (long long)srcidx[3 * rg + 0] * 16);
        const uint4* vp = (const uint4*)(Xbit + (long long)srcidx[3 * rg + 1] * 16);
        const uint4* wp = (const uint4*)(Xbit + (long long)srcidx[3 * rg + 2] * 16);
#pragma unroll
        for (int c = 0; c < 4; ++c) {
          uint4 u = up[c], v = vp[c], w = wp[c];
          a[c] = make_uint4(u.x & v.x & w.x, u.y & v.y & w.y, u.z & v.z & w.z, u.w & v.w & w.w);
        }
      }
    }
#pragma unroll
    for (int c = 0; c < 4; ++c) *(uint4*)(Sb + tid * 20 + c * 4) = a[c];
  }
  __syncthreads();

  const int wave = tid >> 6;
  const int lane = tid & 63;
  const int quad = lane >> 4;
  const int l16 = lane & 15;
  f32x4 acc[8][4];   // [nb][sub]
#pragma unroll
  for (int i = 0; i < 8; ++i)
#pragma unroll
    for (int s = 0; s < 4; ++s) acc[i][s] = (f32x4){0.f, 0.f, 0.f, 0.f};
  const bf16x8* Bf = (const bf16x8*)Bp;
#pragma unroll 2
  for (int kc = 0; kc < 16; ++kc) {
    bf16x8 af[4];
#pragma unroll
    for (int sub = 0; sub < 4; ++sub) {
      unsigned int bw = Sb[(wave * 64 + sub * 16 + l16) * 20 + kc];
      unsigned int byte = (bw >> (quad * 8)) & 0xFFu;
#pragma unroll
      for (int j = 0; j < 4; ++j) {
        unsigned int b2 = (byte >> (2 * j)) & 3u;
        ((unsigned int*)&af[sub])[j] = ((b2 & 1u) | ((b2 & 2u) << 15)) * 0x3F80u;
      }
    }
#pragma unroll
    for (int nb = 0; nb < 8; ++nb) {
      bf16x8 bf = Bf[(kc * 8 + nb) * 64 + lane];
#pragma unroll
      for (int sub = 0; sub < 4; ++sub)
        acc[nb][sub] = __builtin_amdgcn_mfma_f32_16x16x32_bf16(af[sub], bf, acc[nb][sub], 0, 0, 0);
    }
  }

  float bia[8], aw[8];
#pragma unroll
  for (int nb = 0; nb < 8; ++nb) {
    int col128 = nb * 16 + l16;
    int hh = col128 >> 6, col = col128 & 63;
    bia[nb] = bvec[(head_lo + hh) * 64 + col];
    aw[nb] = a2w[(head_lo + hh) * 64 + col];
  }
  float blo = a2b[head_lo], bhi = a2b[head_lo + 1];
#pragma unroll
  for (int sub = 0; sub < 4; ++sub) {
    float plo[4] = {0.f, 0.f, 0.f, 0.f};
    float phi[4] = {0.f, 0.f, 0.f, 0.f};
#pragma unroll
    for (int nb = 0; nb < 8; ++nb) {
      int col128 = nb * 16 + l16;
      int hh = col128 >> 6, col = col128 & 63;
      __half* hdst = hh ? h_hi : h_lo;
#pragma unroll
      for (int reg = 0; reg < 4; ++reg) {
        int rg = m0 + wave * 64 + sub * 16 + quad * 4 + reg;   // C/D: row=quad*4+reg, col=l16
        float v = acc[nb][sub][reg] + bia[nb];
        if (rg < M) hdst[(long long)rg * 64 + col] = __float2half(v);
        if (hh) phi[reg] += v * aw[nb]; else plo[reg] += v * aw[nb];
      }
    }
#pragma unroll
    for (int off = 1; off < 16; off <<= 1) {
#pragma unroll
      for (int reg = 0; reg < 4; ++reg) {
        plo[reg] += __shfl_xor(plo[reg], off);
        phi[reg] += __shfl_xor(phi[reg], off);
      }
    }
    if (l16 == 0) {
#pragma unroll
      for (int reg = 0; reg < 4; ++reg) {
        int rg = m0 + wave * 64 + sub * 16 + quad * 4 + reg;
        if (rg < M) {
          e_lo[rg] = __expf(plo[reg] + blo);   // |s2| small by construction: no max needed
          e_hi[rg] = __expf(phi[reg] + bhi);
        }
      }
    }
  }
}

// ---------- entry decode shared by partition passes ----------
template <bool NEED_VAL>
__device__ __forceinline__ void decode_entry(
    int g, const int* __restrict__ r0, const int* __restrict__ r1a,
    const int* __restrict__ r1b, const int* __restrict__ r2,
    const int* __restrict__ rb1, const int* __restrict__ rb2, int& row, int& val) {
  if (g < 600000) { int l = g; row = SEG_L0 + r0[l]; if (NEED_VAL) val = r0[NNZ0 + l]; }
  else if (g < 1600000) { int l = g - 600000; row = SEG_L1A + r1a[l]; if (NEED_VAL) val = r1a[NNZ1 + l]; }
  else if (g < 2600000) { int l = g - 1600000; row = SEG_L1B + r1b[l]; if (NEED_VAL) val = r1b[NNZ1 + l]; }
  else if (g < 3200000) { int l = g - 2600000; row = SEG_L2 + r2[l]; if (NEED_VAL) val = r2[NNZ2 + l]; }
  else if (g < 3600000) { int l = g - 3200000; row = SEG_B1 + rb1[l]; val = l; }   // B1: entry id
  else { int l = g - 3600000; row = SEG_B2 + rb2[l]; val = l; }                    // B2: entry id
}

// ---------- pass 1: per-(block, coarse-bucket) histogram via LDS ----------
__global__ __launch_bounds__(256) void blkhist_kernel(
    const int* __restrict__ r0, const int* __restrict__ r1a, const int* __restrict__ r1b,
    const int* __restrict__ r2, const int* __restrict__ rb1, const int* __restrict__ rb2,
    int* __restrict__ bh) {
  __shared__ int hcnt[CB];
  int blk = blockIdx.x;
  for (int i = threadIdx.x; i < CB; i += 256) hcnt[i] = 0;
  __syncthreads();
  int g0 = blk * EPB;
  int g1 = g0 + EPB; if (g1 > TOT_E) g1 = TOT_E;
  for (int g = g0 + threadIdx.x; g < g1; g += 256) {
    int row, val;
    decode_entry<false>(g, r0, r1a, r1b, r2, rb1, rb2, row, val);
    atomicAdd(&hcnt[row >> CB_SHIFT], 1);
  }
  __syncthreads();
  for (int i = threadIdx.x; i < CB; i += 256) bh[i * NBLK + blk] = hcnt[i];
}

// ---------- 3-phase scan (parameterized size) ----------
__global__ __launch_bounds__(256) void scan_partial_kernel(const int* __restrict__ cnt,
                                                           int* __restrict__ bsum, int n) {
  __shared__ int s[256];
  int b = blockIdx.x, t = threadIdx.x;
  int base = b * SCAN_CHUNK + t * 16;
  int sum = 0;
#pragma unroll
  for (int i = 0; i < 16; ++i) {
    int idx = base + i;
    if (idx < n) sum += cnt[idx];
  }
  s[t] = sum;
  __syncthreads();
  for (int off = 128; off > 0; off >>= 1) {
    if (t < off) s[t] += s[t + off];
    __syncthreads();
  }
  if (t == 0) bsum[b] = s[0];
}

__global__ __launch_bounds__(256) void scan_bsum_kernel(int* __restrict__ bsum, int nb) {
  __shared__ int s[256];
  int t = threadIdx.x;
  int v = (t < nb) ? bsum[t] : 0;
  s[t] = v;
  __syncthreads();
  for (int off = 1; off < 256; off <<= 1) {
    int u = (t >= off) ? s[t - off] : 0;
    __syncthreads();
    s[t] += u;
    __syncthreads();
  }
  if (t < nb) bsum[t] = (t == 0) ? 0 : s[t - 1];
  if (t == 0) bsum[nb] = s[nb - 1];
}

__global__ __launch_bounds__(256) void scan_write_kernel(const int* __restrict__ cnt,
                                                         const int* __restrict__ bsum,
                                                         int* __restrict__ gout, int n, int nb) {
  __shared__ int s[256];
  int b = blockIdx.x, t = threadIdx.x;
  int base = b * SCAN_CHUNK + t * 16;
  int loc[16];
  int sum = 0;
#pragma unroll
  for (int i = 0; i < 16; ++i) {
    int idx = base + i;
    int v = (idx < n) ? cnt[idx] : 0;
    loc[i] = sum;
    sum += v;
  }
  s[t] = sum;
  __syncthreads();
  for (int off = 1; off < 256; off <<= 1) {
    int u = (t >= off) ? s[t - off] : 0;
    __syncthreads();
    s[t] += u;
    __syncthreads();
  }
  int toff = bsum[b] + ((t == 0) ? 0 : s[t - 1]);
#pragma unroll
  for (int i = 0; i < 16; ++i) {
    int idx = base + i;
    if (idx < n) gout[idx] = toff + loc[i];
  }
  if (b == 0 && t == 0) gout[n] = bsum[nb];
}

// ---------- pass 2: write (row,val) into this block's PRIVATE per-bucket runs ----------
__global__ __launch_bounds__(256) void stage_part_kernel(
    const int* __restrict__ r0, const int* __restrict__ r1a, const int* __restrict__ r1b,
    const int* __restrict__ r2, const int* __restrict__ rb1, const int* __restrict__ rb2,
    const int* __restrict__ bhoff, int2* __restrict__ stage) {
  __shared__ int lcur[CB];
  int blk = blockIdx.x;
  for (int i = threadIdx.x; i < CB; i += 256) lcur[i] = bhoff[i * NBLK + blk];
  __syncthreads();
  int g0 = blk * EPB;
  int g1 = g0 + EPB; if (g1 > TOT_E) g1 = TOT_E;
  for (int g = g0 + threadIdx.x; g < g1; g += 256) {
    int row, val;
    decode_entry<true>(g, r0, r1a, r1b, r2, rb1, rb2, row, val);
    int pos = atomicAdd(&lcur[row >> CB_SHIFT], 1);   // run is block-private
    stage[pos] = make_int2(row, val);
  }
}

// ---------- pass 3: per coarse-bucket: derive gscan locally + scatter pool slice ----------
__global__ __launch_bounds__(256) void fill_cb_kernel(
    const int* __restrict__ bhoff, const int2* __restrict__ stage,
    int* __restrict__ gscan, int* __restrict__ pool) {
  __shared__ int hist[1 << CB_SHIFT];   // 2048 row counters -> offsets -> cursors
  __shared__ int sums[256];
  const int cb = blockIdx.x;
  const int t = threadIdx.x;
  const int base_row = cb << CB_SHIFT;
  int nrows = CNT_TOT - base_row;
  if (nrows > (1 << CB_SHIFT)) nrows = 1 << CB_SHIFT;
  const int s0 = bhoff[cb * NBLK];
  const int s1 = bhoff[(cb + 1) * NBLK];   // bhoff[BH_N] = TOT_E covers cb == CB-1
  for (int i = t; i < (1 << CB_SHIFT); i += 256) hist[i] = 0;
  __syncthreads();
  for (int i = s0 + t; i < s1; i += 256) atomicAdd(&hist[stage[i].x - base_row], 1);
  __syncthreads();
  // exclusive scan of the 2048 counts; thread t owns slots [8t, 8t+8)
  int loc[8];
  int sum = 0;
#pragma unroll
  for (int j = 0; j < 8; ++j) { loc[j] = sum; sum += hist[t * 8 + j]; }
  sums[t] = sum;
  __syncthreads();
  for (int off = 1; off < 256; off <<= 1) {
    int u = (t >= off) ? sums[t - off] : 0;
    __syncthreads();
    sums[t] += u;
    __syncthreads();
  }
  int pre = (t == 0) ? 0 : sums[t - 1];
#pragma unroll
  for (int j = 0; j < 8; ++j) hist[t * 8 + j] = s0 + pre + loc[j];   // row start offsets
  __syncthreads();
  for (int i = t; i < nrows; i += 256) gscan[base_row + i] = hist[i];
  if (cb == CB - 1 && t == 0) gscan[CNT_TOT] = TOT_E;
  __syncthreads();
  for (int i = s0 + t; i < s1; i += 256) {
    int2 rv = stage[i];
    int pos = atomicAdd(&hist[rv.x - base_row], 1);
    pool[pos] = rv.y;   // slice is block-private: stays in one L2, written once
  }
}

// ---------- dual-table gather over one CSR row, 4x unrolled for MLP ----------
__device__ __forceinline__ void dual_gather_row(
    const int* __restrict__ col, int p0, int p1, int lane,
    const float* __restrict__ ea, const __half* __restrict__ ha,
    const float* __restrict__ eb, const __half* __restrict__ hb,
    float& za, float& aa, float& zb, float& ab) {
  int p = p0;
  for (; p + 4 <= p1; p += 4) {
    int c0 = col[p + 0], c1 = col[p + 1], c2 = col[p + 2], c3 = col[p + 3];
    float wa0 = ea[c0], wa1 = ea[c1], wa2 = ea[c2], wa3 = ea[c3];
    float wb0 = eb[c0], wb1 = eb[c1], wb2 = eb[c2], wb3 = eb[c3];
    float va0 = __half2float(ha[(long long)c0 * 64 + lane]);
    float va1 = __half2float(ha[(long long)c1 * 64 + lane]);
    float va2 = __half2float(ha[(long long)c2 * 64 + lane]);
    float va3 = __half2float(ha[(long long)c3 * 64 + lane]);
    float vb0 = __half2float(hb[(long long)c0 * 64 + lane]);
    float vb1 = __half2float(hb[(long long)c1 * 64 + lane]);
    float vb2 = __half2float(hb[(long long)c2 * 64 + lane]);
    float vb3 = __half2float(hb[(long long)c3 * 64 + lane]);
    za += (wa0 + wa1) + (wa2 + wa3);
    zb += (wb0 + wb1) + (wb2 + wb3);
    aa += wa0 * va0 + wa1 * va1 + wa2 * va2 + wa3 * va3;
    ab += wb0 * vb0 + wb1 * vb1 + wb2 * vb2 + wb3 * vb3;
  }
  for (; p < p1; ++p) {
    int c = col[p];
    float wa = ea[c], wb = eb[c];
    za += wa; zb += wb;
    aa += wa * __half2float(ha[(long long)c * 64 + lane]);
    ab += wb * __half2float(hb[(long long)c * 64 + lane]);
  }
}

// ---------- SAT dual (L0, L2): one traversal, expv precomputed per node ----------
template <typename OutT>
__global__ __launch_bounds__(256) void sat_dual_z_kernel(
    const int* __restrict__ rowptr, const int* __restrict__ col,
    const float* __restrict__ ea, const __half* __restrict__ ha,
    const float* __restrict__ eb, const __half* __restrict__ hb,
    const float* __restrict__ pw, OutT* __restrict__ out, int n) {
  int row = blockIdx.x * 4 + (threadIdx.x >> 6);
  if (row >= n) return;
  int lane = threadIdx.x & 63;
  int p0 = rowptr[row], p1 = rowptr[row + 1];
  float za = 0.f, zb = 0.f, aa = 0.f, ab = 0.f;
  dual_gather_row(col, p0, p1, lane, ea, ha, eb, hb, za, aa, zb, ab);
  float r = (za > 0.f ? aa / za : 0.f) + (zb > 0.f ? ab / zb : 0.f);
  float pv = pw[0];
  r = r >= 0.f ? r : pv * r;   // prelu
  out[(long long)row * 64 + lane] = (OutT)r;
}

// ---------- H2t = H2 @ triW via f16 MFMA ----------
__global__ __launch_bounds__(256) void tri_mfma_kernel(
    const __half* __restrict__ H2, const __half* __restrict__ Wt,
    __half* __restrict__ H2t, int n) {
  const int tid = threadIdx.x;
  const int m0 = blockIdx.x * 64;
  const int wave = tid >> 6;
  const int lane = tid & 63;
  const int quad = lane >> 4;
  const int l16 = lane & 15;
  const int arow = m0 + wave * 16 + l16;
  f32x4 acc[4];
#pragma unroll
  for (int i = 0; i < 4; ++i) acc[i] = (f32x4){0.f, 0.f, 0.f, 0.f};
  const f16x8* Wf = (const f16x8*)Wt;
#pragma unroll
  for (int kc = 0; kc < 2; ++kc) {
    f16x8 af = (f16x8){0, 0, 0, 0, 0, 0, 0, 0};
    if (arow < n) af = *(const f16x8*)((const _Float16*)H2 + (long long)arow * 64 + kc * 32 + quad * 8);
#pragma unroll
    for (int nb = 0; nb < 4; ++nb) {
      f16x8 bf = Wf[(kc * 4 + nb) * 64 + lane];
      acc[nb] = __builtin_amdgcn_mfma_f32_16x16x32_f16(af, bf, acc[nb], 0, 0, 0);
    }
  }
#pragma unroll
  for (int nb = 0; nb < 4; ++nb) {
    int col = nb * 16 + l16;
#pragma unroll
    for (int reg = 0; reg < 4; ++reg) {
      int rg = m0 + wave * 16 + quad * 4 + reg;
      if (rg < n) H2t[(long long)rg * 64 + col] = __float2half(acc[nb][reg]);
    }
  }
}

// ---------- mega edge-row kernel: G = prelu(satL1a + satL1b) + trib + B2 @ H2t ----------
__global__ __launch_bounds__(256) void sat_l1_mega_kernel(
    const int* __restrict__ rp_a, const int* __restrict__ rp_b, const int* __restrict__ rp_B2,
    const int* __restrict__ pool,
    const float* __restrict__ ea, const __half* __restrict__ ha,
    const float* __restrict__ eb, const __half* __restrict__ hb,
    const __half* __restrict__ H2t, const float* __restrict__ trib,
    const float* __restrict__ pw, __half* __restrict__ G, int n) {
  int row = blockIdx.x * 4 + (threadIdx.x >> 6);
  if (row >= n) return;
  int lane = threadIdx.x & 63;
  // head a, 4x unrolled
  float za = 0.f, aa = 0.f;
  {
    int p0 = rp_a[row], p1 = rp_a[row + 1];
    int p = p0;
    for (; p + 4 <= p1; p += 4) {
      int c0 = pool[p + 0], c1 = pool[p + 1], c2 = pool[p + 2], c3 = pool[p + 3];
      float w0 = ea[c0], w1 = ea[c1], w2 = ea[c2], w3 = ea[c3];
      float v0 = __half2float(ha[(long long)c0 * 64 + lane]);
      float v1 = __half2float(ha[(long long)c1 * 64 + lane]);
      float v2 = __half2float(ha[(long long)c2 * 64 + lane]);
      float v3 = __half2float(ha[(long long)c3 * 64 + lane]);
      za += (w0 + w1) + (w2 + w3);
      aa += w0 * v0 + w1 * v1 + w2 * v2 + w3 * v3;
    }
    for (; p < p1; ++p) {
      int c = pool[p];
      float w = ea[c];
      za += w;
      aa += w * __half2float(ha[(long long)c * 64 + lane]);
    }
  }
  // head b, 4x unrolled
  float zb = 0.f, ab = 0.f;
  {
    int p0 = rp_b[row], p1 = rp_b[row + 1];
    int p = p0;
    for (; p + 4 <= p1; p += 4) {
      int c0 = pool[p + 0], c1 = pool[p + 1], c2 = pool[p + 2], c3 = pool[p + 3];
      float w0 = eb[c0], w1 = eb[c1], w2 = eb[c2], w3 = eb[c3];
      float v0 = __half2float(hb[(long long)c0 * 64 + lane]);
      float v1 = __half2float(hb[(long long)c1 * 64 + lane]);
      float v2 = __half2float(hb[(long long)c2 * 64 + lane]);
      float v3 = __half2float(hb[(long long)c3 * 64 + lane]);
      zb += (w0 + w1) + (w2 + w3);
      ab += w0 * v0 + w1 * v1 + w2 * v2 + w3 * v3;
    }
    for (; p < p1; ++p) {
      int c = pool[p];
      float w = eb[c];
      zb += w;
      ab += w * __half2float(hb[(long long)c * 64 + lane]);
    }
  }
  float r = (za > 0.f ? aa / za : 0.f) + (zb > 0.f ? ab / zb : 0.f);
  float pv = pw[0];
  r = r >= 0.f ? r : pv * r;          // H1 = prelu(...)
  // Tm = B2 @ H2t + trib (avg 1.5 entries/row; 2x unroll)
  float tm = trib[lane];
  {
    int p0 = rp_B2[row], p1 = rp_B2[row + 1];
    int p = p0;
    for (; p + 2 <= p1; p += 2) {
      int e0 = pool[p], e1 = pool[p + 1];
      int c0 = e0 / 3, c1 = e1 / 3;
      float s0 = (e0 - 3 * c0 == 1) ? -1.f : 1.f;
      float s1 = (e1 - 3 * c1 == 1) ? -1.f : 1.f;
      float v0 = __half2float(H2t[(long long)c0 * 64 + lane]);
      float v1 = __half2float(H2t[(long long)c1 * 64 + lane]);
      tm += s0 * v0 + s1 * v1;
    }
    for (; p < p1; ++p) {
      int e = pool[p];
      int c = e / 3;
      float s = (e - 3 * c == 1) ? -1.f : 1.f;
      tm += s * __half2float(H2t[(long long)c * 64 + lane]);
    }
  }
  G[(long long)row * 64 + lane] = __float2half(r + tm);
}

// ---------- out = (H0 + B1 @ G) / 3, B1 loop 4x unrolled ----------
__global__ __launch_bounds__(256) void final_kernel(
    const int* __restrict__ rowptr, const int* __restrict__ ent,
    const float* __restrict__ H0, const __half* __restrict__ G,
    float* __restrict__ out, int n) {
  int row = blockIdx.x * 4 + (threadIdx.x >> 6);
  if (row >= n) return;
  int lane = threadIdx.x & 63;
  int p0 = rowptr[row], p1 = rowptr[row + 1];
  float acc = H0[(long long)row * 64 + lane];
  int p = p0;
  for (; p + 4 <= p1; p += 4) {
    int e0 = ent[p], e1 = ent[p + 1], e2 = ent[p + 2], e3 = ent[p + 3];
    float s0 = (e0 & 1) ? -1.f : 1.f;
    float s1 = (e1 & 1) ? -1.f : 1.f;
    float s2 = (e2 & 1) ? -1.f : 1.f;
    float s3 = (e3 & 1) ? -1.f : 1.f;
    float v0 = __half2float(G[(long long)(e0 >> 1) * 64 + lane]);
    float v1 = __half2float(G[(long long)(e1 >> 1) * 64 + lane]);
    float v2 = __half2float(G[(long long)(e2 >> 1) * 64 + lane]);
    float v3 = __half2float(G[(long long)(e3 >> 1) * 64 + lane]);
    acc += s0 * v0 + s1 * v1 + s2 * v2 + s3 * v3;
  }
  for (; p < p1; ++p) {
    int e = ent[p];
    float s = (e & 1) ? -1.f : 1.f;
    acc += s * __half2float(G[(long long)(e >> 1) * 64 + lane]);
  }
  out[(long long)row * 64 + lane] = acc * (1.0f / 3.0f);
}

extern "C" void kernel_launch(void* const* d_in, const int* in_sizes, int n_in,
                              void* d_out, int out_size, void* d_ws, size_t ws_size,
                              hipStream_t stream) {
  const float* X0 = (const float*)d_in[0];
  const int* E1 = (const int*)d_in[1];
  const int* T2 = (const int*)d_in[2];
  const int* L0i = (const int*)d_in[3];
  const int* L1ai = (const int*)d_in[4];
  const int* L1bi = (const int*)d_in[5];
  const int* L2i = (const int*)d_in[6];
  const int* B1i = (const int*)d_in[7];
  const int* B2i = (const int*)d_in[9];
  const float* W = (const float*)d_in[11];
  const float* bvec = (const float*)d_in[12];
  // a1_w/a1_b are mathematically dead: s1[r] cancels in the row softmax.
  const float* a2w = (const float*)d_in[15];
  const float* a2b = (const float*)d_in[16];
  const float* pw = (const float*)d_in[17];
  const float* triW = (const float*)d_in[18];
  const float* trib = (const float*)d_in[19];
  float* out = (float*)d_out;

  char* base = (char*)d_ws;
  size_t off = 0;
  auto alloc = [&](size_t bytes) -> void* {
    void* p = base + off;
    off += (bytes + 255) & ~(size_t)255;
    return p;
  };
  unsigned int* Xbit = (unsigned int*)alloc((size_t)N0 * 16 * 4);
  unsigned short* Bp = (unsigned short*)alloc((size_t)3 * 65536 * 2);
  __half* Wt = (__half*)alloc((size_t)4096 * 2);
  __half* h0 = (__half*)alloc((size_t)N0 * 64 * 2);
  __half* h1 = (__half*)alloc((size_t)N0 * 64 * 2);
  __half* h2 = (__half*)alloc((size_t)N1 * 64 * 2);
  __half* h3 = (__half*)alloc((size_t)N1 * 64 * 2);
  __half* h4 = (__half*)alloc((size_t)N2 * 64 * 2);
  __half* h5 = (__half*)alloc((size_t)N2 * 64 * 2);
  float* e0 = (float*)alloc((size_t)N0 * 4);
  float* e1 = (float*)alloc((size_t)N0 * 4);
  float* e2 = (float*)alloc((size_t)N1 * 4);
  float* e3 = (float*)alloc((size_t)N1 * 4);
  float* e4 = (float*)alloc((size_t)N2 * 4);
  float* e5 = (float*)alloc((size_t)N2 * 4);
  float* H0 = (float*)alloc((size_t)N0 * 64 * 4);
  __half* H2 = (__half*)alloc((size_t)N2 * 64 * 2);
  __half* H2t = (__half*)alloc((size_t)N2 * 64 * 2);
  __half* G = (__half*)alloc((size_t)N1 * 64 * 2);
  int* gscan = (int*)alloc((size_t)(CNT_TOT + 1) * 4);
  int* pool = (int*)alloc((size_t)TOT_E * 4);
  int2* stage = (int2*)alloc((size_t)TOT_E * 8);
  int* bh = (int*)alloc((size_t)BH_N * 4);
  int* bhoff = (int*)alloc((size_t)(BH_N + 1) * 4);
  int* bsum = (int*)alloc((size_t)(BH_SCAN_BLOCKS + 1) * 4);

  pack_bits_kernel<<<(N0 + 3) / 4, 256, 0, stream>>>(X0, Xbit);
  pack_w_kernel<<<(3 * 65536 + 255) / 256, 256, 0, stream>>>(W, Bp);
  pack_wt_kernel<<<16, 256, 0, stream>>>(triW, Wt);

  gemm_sat_kernel<1><<<(N0 + 255) / 256, 256, 0, stream>>>(Xbit, nullptr, Bp, bvec, a2w, a2b, 0, N0, h0, h1, e0, e1);
  gemm_sat_kernel<2><<<(N1 + 255) / 256, 256, 0, stream>>>(Xbit, E1, Bp + 65536, bvec, a2w, a2b, 2, N1, h2, h3, e2, e3);
  gemm_sat_kernel<3><<<(N2 + 255) / 256, 256, 0, stream>>>(Xbit, T2, Bp + 2 * 65536, bvec, a2w, a2b, 4, N2, h4, h5, e4, e5);

  // radix-partition CSR build (no row-level global histogram needed)
  blkhist_kernel<<<NBLK, 256, 0, stream>>>(L0i, L1ai, L1bi, L2i, B1i, B2i, bh);
  scan_partial_kernel<<<BH_SCAN_BLOCKS, 256, 0, stream>>>(bh, bsum, BH_N);
  scan_bsum_kernel<<<1, 256, 0, stream>>>(bsum, BH_SCAN_BLOCKS);
  scan_write_kernel<<<BH_SCAN_BLOCKS, 256, 0, stream>>>(bh, bsum, bhoff, BH_N, BH_SCAN_BLOCKS);
  stage_part_kernel<<<NBLK, 256, 0, stream>>>(L0i, L1ai, L1bi, L2i, B1i, B2i, bhoff, stage);
  fill_cb_kernel<<<CB, 256, 0, stream>>>(bhoff, stage, gscan, pool);

  const int* rp0 = gscan + SEG_L0;
  const int* rp1a = gscan + SEG_L1A;
  const int* rp1b = gscan + SEG_L1B;
  const int* rp2 = gscan + SEG_L2;
  const int* rpB1 = gscan + SEG_B1;
  const int* rpB2 = gscan + SEG_B2;

  sat_dual_z_kernel<float><<<(N0 + 3) / 4, 256, 0, stream>>>(rp0, pool, e0, h0, e1, h1, pw, H0, N0);
  sat_dual_z_kernel<__half><<<(N2 + 3) / 4, 256, 0, stream>>>(rp2, pool, e4, h4, e5, h5, pw, H2, N2);
  tri_mfma_kernel<<<(N2 + 63) / 64, 256, 0, stream>>>(H2, Wt, H2t, N2);
  sat_l1_mega_kernel<<<(N1 + 3) / 4, 256, 0, stream>>>(rp1a, rp1b, rpB2, pool, e2, h2, e3, h3,
                                                       H2t, trib, pw, G, N1);
  final_kernel<<<(N0 + 3) / 4, 256, 0, stream>>>(rpB1, pool, H0, G, out, N0);
}